// Round 8
// baseline (2287.260 us; speedup 1.0000x reference)
//
#include <hip/hip_runtime.h>

// ---------------- types / helpers ----------------
typedef unsigned short u16;
typedef unsigned long long u64;
typedef short short8 __attribute__((ext_vector_type(8)));

__device__ __forceinline__ float b2f(u16 u) {
    unsigned x = ((unsigned)u) << 16;
    return __builtin_bit_cast(float, x);
}
__device__ __forceinline__ u16 f2b(float f) {
    unsigned u = __builtin_bit_cast(unsigned, f);
    u += 0x7FFFu + ((u >> 16) & 1u);   // RNE
    return (u16)(u >> 16);
}
__device__ __forceinline__ float lo16(unsigned u) {   // low bf16 -> f32
    return __builtin_bit_cast(float, u << 16);
}
__device__ __forceinline__ float hi16(unsigned u) {   // high bf16 -> f32
    return __builtin_bit_cast(float, u & 0xFFFF0000u);
}
__device__ __forceinline__ float sigm(float x) { return 1.f / (1.f + __expf(-x)); }
__device__ __forceinline__ float tanh_(float x) { return 1.f - 2.f / (__expf(2.f * x) + 1.f); }

// ---------------- problem constants ----------------
#define T_STEPS 128
#define BATCH   32
#define MEMPAD  68       // mem row stride in floats
#define WKPAD   264      // wkeyT row pad (bf16 elems)
#define KREG    128      // W' rows resident in VGPRs
#define KTOT    320      // 64 (read) + 256 (h)

// ---------------- workspace layout (bytes) ----------------
#define WS_LOSS     128
#define WS_FLAG     160
#define WS_ZSET     41088                     // memset range end (loss, flag, slack)
// normalized fp32 inputs
#define WS_XSF      41216                     // 524288 f32 (xs; later overwritten by Wpk)
#define WS_WPK      41216                     // u32 [320][512] packed bf16 W' = 655360 B
#define WS_MEM0F    2138368                   // 524288 f32
#define WS_WLF      4235520                   // 655360 f32
#define WS_BLF      6856960                   // 1024 f32
#define WS_WPREF    6861056                   // 32768 f32
#define WS_BPREF    6992128                   // 128 f32
#define WS_WKEYF    6992640                   // 16384 f32
#define WS_WBETAF   7058176                   // 256 f32
#define WS_WTEACHF  7059200                   // 16384 f32
#define WS_WROF     7124736                   // 32768 f32
// derived
#define WS_XW       7255808                   // f32 [4096][1024] = 16777216
#define WS_WKT      24295168                  // f32 [256][64]    = 65536
#define WS_WROEFF   24360704                  // f32 [64][128]    = 32768
#define WS_HS       24393472                  // f32 [4096][256]  = 4194304
#define WS_RS       28587776                  // f32 [4096][64]   = 1048576

// ---------------- LDS layout (bytes), dnc_main ----------------
#define MEM_OFF  0         // f32 [256][68]   69632
#define WK_OFF   69632     // u16 [64][264]   33792  -> 103424
#define Z_OFF    103424    // f32 [1024]       4096  -> 107520
#define HRF_OFF  107520    // f32 [320]        1280  -> 108800  (0..63 r, 64..319 h)
#define HBB_OFF  108800    // u16 [256]         512  -> 109312
#define WB_OFF   109312    // f32 [256]        1024  -> 110336
#define KV_OFF   110336    // f32 [64]          256  -> 110592
#define WW_OFF   110592    // f32 [256]        1024  -> 111616
#define KP_OFF   111616    // f32 [4][64]      1024  -> 112640
#define RP_OFF   112640    // f32 [4][64]      1024  -> 113664
#define WR_OFF   113664    // f32 [16]           64  -> 113728
#define SC_OFF   113728    // f32 [16]           64  -> 113792
#define LDS_TOTAL 113792

// ---------------- dtype probe: f32 vs bf16 ----------------
__global__ void dnc_probe(const u16* __restrict__ xs_u16, char* __restrict__ ws) {
    __shared__ int cnt;
    if (threadIdx.x == 0) cnt = 0;
    __syncthreads();
    int c = 0;
    for (int i = threadIdx.x; i < 1024; i += 256) {
        int e = (xs_u16[i] >> 7) & 0xFF;
        if (e >= 96 && e <= 135) c++;
    }
    atomicAdd(&cnt, c);
    __syncthreads();
    if (threadIdx.x == 0) *(int*)(ws + WS_FLAG) = (cnt > 820) ? 1 : 0;   // 1 = bf16
}

// ---------------- normalize all inputs to fp32 in ws ----------------
__global__ void dnc_normalize(const void* s0, const void* s1, const void* s2, const void* s3,
                              const void* s4, const void* s5, const void* s6, const void* s7,
                              const void* s8, const void* s9, char* __restrict__ ws) {
    const void* srcs[10] = {s0, s1, s2, s3, s4, s5, s6, s7, s8, s9};
    const int sizes[10] = {524288, 524288, 655360, 1024, 32768, 128, 16384, 256, 16384, 32768};
    const int bases[10] = {WS_XSF, WS_MEM0F, WS_WLF, WS_BLF, WS_WPREF, WS_BPREF,
                           WS_WKEYF, WS_WBETAF, WS_WTEACHF, WS_WROF};
    const int bf = *(const int*)(ws + WS_FLAG);
    const int gt = blockIdx.x * 256 + threadIdx.x, gs = gridDim.x * 256;
    for (int s = 0; s < 10; ++s) {
        float* dst = (float*)(ws + bases[s]);
        const int n = sizes[s];
        if (bf) {
            const u16* p = (const u16*)srcs[s];
            for (int i = gt; i < n; i += gs) dst[i] = b2f(p[i]);
        } else {
            const float* p = (const float*)srcs[s];
            for (int i = gt; i < n; i += gs) dst[i] = p[i];
        }
    }
}

// ---------------- prologue: xW 2D-blocked GEMM + epilogue weight folds ----------------
// wg < 256: 128x128 tile of xW = xs(4096x128) @ Wl[0:128](128x1024) + b.
// wg 256..271: Wkt; 272..279: WroEff.
__global__ void dnc_prologue(char* __restrict__ ws) {
    extern __shared__ float xls[];   // [128][129]
    const float* XSF     = (const float*)(ws + WS_XSF);
    const float* WLF     = (const float*)(ws + WS_WLF);
    const float* BLF     = (const float*)(ws + WS_BLF);
    const float* WKEYF   = (const float*)(ws + WS_WKEYF);
    const float* WTEACHF = (const float*)(ws + WS_WTEACHF);
    const float* WROF    = (const float*)(ws + WS_WROF);
    float* xW  = (float*)(ws + WS_XW);
    float* Wkt = (float*)(ws + WS_WKT);
    float* Wre = (float*)(ws + WS_WROEFF);
    const int wg = blockIdx.x, tid = threadIdx.x;
    if (wg < 256) {
        const int rb = wg >> 3, cb = wg & 7;
        const float4* xsrc = (const float4*)(XSF + (size_t)rb * 16384);
        for (int i = tid; i < 4096; i += 256) {
            float4 v = xsrc[i];
            int row = i >> 5, c4 = (i & 31) * 4;
            float* d = xls + row * 129 + c4;
            d[0] = v.x; d[1] = v.y; d[2] = v.z; d[3] = v.w;
        }
        __syncthreads();
        const int tr = tid >> 4, tc = tid & 15;
        const int c0 = cb * 128 + tc * 8;
        float acc[8][8];
#pragma unroll
        for (int rr = 0; rr < 8; ++rr)
#pragma unroll
            for (int cc = 0; cc < 8; ++cc) acc[rr][cc] = BLF[c0 + cc];
        for (int k = 0; k < 128; ++k) {
            float4 wA = *(const float4*)(WLF + (size_t)k * 1024 + c0);
            float4 wB = *(const float4*)(WLF + (size_t)k * 1024 + c0 + 4);
            float w[8] = {wA.x, wA.y, wA.z, wA.w, wB.x, wB.y, wB.z, wB.w};
#pragma unroll
            for (int rr = 0; rr < 8; ++rr) {
                float xv = xls[(tr * 8 + rr) * 129 + k];
#pragma unroll
                for (int cc = 0; cc < 8; ++cc) acc[rr][cc] += xv * w[cc];
            }
        }
#pragma unroll
        for (int rr = 0; rr < 8; ++rr) {
            size_t o = (size_t)(rb * 128 + tr * 8 + rr) * 1024 + c0;
            *(float4*)(xW + o)     = make_float4(acc[rr][0], acc[rr][1], acc[rr][2], acc[rr][3]);
            *(float4*)(xW + o + 4) = make_float4(acc[rr][4], acc[rr][5], acc[rr][6], acc[rr][7]);
        }
    } else if (wg < 272) {
        const int i = (wg - 256) * 1024 + tid * 4;
#pragma unroll
        for (int e = 0; e < 4; ++e) Wkt[i + e] = WKEYF[i + e] - WTEACHF[i + e];
    } else if (wg < 280) {
        const int i = (wg - 272) * 1024 + tid * 4;
#pragma unroll
        for (int e = 0; e < 4; ++e) {
            int m = (i + e) >> 7, c = (i + e) & 127;
            float s = 0.f;
#pragma unroll
            for (int rr = 0; rr < 4; ++rr) s += WROF[(4 * m + rr) * 128 + c];
            Wre[i + e] = s;
        }
    }
}

// ---------------- pack W' to bf16 pairs: Wpk[k][c2] = (bf16(W'[k][2c2+1])<<16)|bf16(W'[k][2c2]) ----------------
// W'[k] = (k<64) ? sum_{rr<4} Wl[128+4k+rr] (read-head fold) : Wl[384+k-64].
// Runs AFTER prologue; overwrites the xs region (no longer needed).
__global__ void dnc_pack(char* __restrict__ ws) {
    const float* WLF = (const float*)(ws + WS_WLF);
    unsigned* Wpk = (unsigned*)(ws + WS_WPK);
    const int k = blockIdx.x, tid = threadIdx.x;
#pragma unroll
    for (int j = 0; j < 2; ++j) {
        int c2 = tid * 2 + j;
        float lo, hi;
        if (k < 64) {
            lo = 0.f; hi = 0.f;
#pragma unroll
            for (int rr = 0; rr < 4; ++rr) {
                const float* row = WLF + (size_t)(128 + 4 * k + rr) * 1024;
                lo += row[2 * c2]; hi += row[2 * c2 + 1];
            }
        } else {
            const float* row = WLF + (size_t)(384 + k - 64) * 1024;
            lo = row[2 * c2]; hi = row[2 * c2 + 1];
        }
        Wpk[k * 512 + c2] = ((unsigned)f2b(hi) << 16) | (unsigned)f2b(lo);
    }
}

// ---------------- main: 32 INDEPENDENT wgs, one batch each, NO cross-wg sync ----------------
__global__ __launch_bounds__(256, 1) void dnc_main(char* __restrict__ ws) {
    extern __shared__ char smem[];
    float* memA = (float*)(smem + MEM_OFF);
    u16*  wkeyT = (u16*)(smem + WK_OFF);
    float* z_lds = (float*)(smem + Z_OFF);
    float* hrF  = (float*)(smem + HRF_OFF);    // [320] f32: 0..63 r, 64..319 h
    u16*  hbB   = (u16*)(smem + HBB_OFF);      // [256] bf16 h (for M phase)
    float* wbF  = (float*)(smem + WB_OFF);
    float* kv   = (float*)(smem + KV_OFF);
    float* wwts = (float*)(smem + WW_OFF);
    float* kpart = (float*)(smem + KP_OFF);
    float* rp   = (float*)(smem + RP_OFF);
    float* wred = (float*)(smem + WR_OFF);
    float* sc   = (float*)(smem + SC_OFF);

    const int tid  = threadIdx.x;
    const int b    = blockIdx.x;     // batch
    const int lane = tid & 63;
    const int wid  = tid >> 6;

    const unsigned* Wpk = (const unsigned*)(ws + WS_WPK);
    const uint2* Wpk2   = (const uint2*)Wpk;           // row stride 256 uint2
    const float* xWF    = (const float*)(ws + WS_XW);
    const float* WKEYF  = (const float*)(ws + WS_WKEYF);
    const float* WBETAF = (const float*)(ws + WS_WBETAF);
    const float* MEM0F  = (const float*)(ws + WS_MEM0F);
    float* HsF = (float*)(ws + WS_HS);
    float* RsF = (float*)(ws + WS_RS);

    // ---- one-time init ----
    for (int i = tid; i < 256 * 64; i += 256) {   // wkeyT[m][k] = Wkey[k][m] (bf16)
        int k = i >> 6, m = i & 63;
        wkeyT[m * WKPAD + k] = f2b(WKEYF[i]);
    }
    wbF[tid] = WBETAF[tid];
    for (int i = tid; i < 320; i += 256) hrF[i] = 0.f;   // h(-1)=0, r(-1)=0
    for (int i = tid; i < 256 * 64; i += 256) {   // mem state fp32
        int n = i >> 6, m = i & 63;
        memA[n * MEMPAD + m] = MEM0F[b * 16384 + i];
    }
    // W' rows 0..127 resident in VGPRs: this thread's 4 columns (4tid..4tid+3)
    uint2 wreg2[KREG];
#pragma unroll
    for (int k = 0; k < KREG; ++k) wreg2[k] = Wpk2[k * 256 + tid];
    float c_reg = 0.f;                            // LSTM cell state for unit u = tid
    __syncthreads();

    for (int t = 0; t < T_STEPS; ++t) {
        // issue xW gate loads for this step (consumed after GEMV)
        const size_t xb = (size_t)(t * BATCH + b) * 1024 + tid;
        float xg0 = xWF[xb];
        float xg1 = xWF[xb + 256];
        float xg2 = xWF[xb + 512];
        float xg3 = xWF[xb + 768];

        // ---- GEMV: z[4tid..4tid+3] = sum_k hr[k] * W'[k][c] ----
        float a0 = 0.f, a1 = 0.f, a2 = 0.f, a3 = 0.f;
        {
            const float4* hr4 = (const float4*)hrF;
#pragma unroll
            for (int kq = 0; kq < KREG / 4; ++kq) {      // register-resident rows
                float4 h4 = hr4[kq];
                float hh[4] = {h4.x, h4.y, h4.z, h4.w};
#pragma unroll
                for (int j = 0; j < 4; ++j) {
                    uint2 w = wreg2[kq * 4 + j];
                    float h = hh[j];
                    a0 += h * lo16(w.x); a1 += h * hi16(w.x);
                    a2 += h * lo16(w.y); a3 += h * hi16(w.y);
                }
            }
            // streamed rows 128..319 (L2-resident, shared by 4 wgs/XCD)
#pragma unroll 1
            for (int kc = 0; kc < (KTOT - KREG) / 16; ++kc) {
                uint2 st[16];
#pragma unroll
                for (int i = 0; i < 16; ++i)
                    st[i] = Wpk2[(KREG + kc * 16 + i) * 256 + tid];
#pragma unroll
                for (int i = 0; i < 16; ++i) {
                    float h = hrF[KREG + kc * 16 + i];
                    uint2 w = st[i];
                    a0 += h * lo16(w.x); a1 += h * hi16(w.x);
                    a2 += h * lo16(w.y); a3 += h * hi16(w.y);
                }
            }
        }
        *(float4*)(z_lds + 4 * tid) = make_float4(a0, a1, a2, a3);
        __syncthreads();

        // ---- LSTM pointwise: unit u = tid ----
        {
            float iv = z_lds[tid]       + xg0;
            float fv = z_lds[256 + tid] + xg1;
            float gv = z_lds[512 + tid] + xg2;
            float ov = z_lds[768 + tid] + xg3;
            float cn = sigm(fv) * c_reg + sigm(iv) * tanh_(gv);
            float hn = sigm(ov) * tanh_(cn);
            c_reg = cn;
            hbB[tid] = f2b(hn);
            hrF[64 + tid] = hn;
            HsF[(size_t)(t * BATCH + b) * 256 + tid] = hn;   // epilogue-only
        }
        __syncthreads();

        // ---- M phase (all intra-wg) ----
        // k GEMV: wave wid = k-part, lane = m
        {
            float a = 0.f;
#pragma unroll
            for (int i = 0; i < 8; ++i) {
                short8 w8 = *(const short8*)(wkeyT + lane * WKPAD + wid * 64 + i * 8);
                short8 h8 = *(const short8*)(hbB + wid * 64 + i * 8);
#pragma unroll
                for (int e = 0; e < 8; ++e)
                    a += b2f((u16)h8[e]) * b2f((u16)w8[e]);
            }
            kpart[wid * 64 + lane] = a;
        }
        // beta partial
        {
            float bp = b2f(hbB[tid]) * wbF[tid];
#pragma unroll
            for (int off = 32; off > 0; off >>= 1) bp += __shfl_xor(bp, off, 64);
            if (lane == 0) wred[12 + wid] = bp;
        }
        __syncthreads();
        if (tid < 64) {   // finalize k, ||k||
            float kk = kpart[tid] + kpart[64 + tid] + kpart[128 + tid] + kpart[192 + tid];
            kv[tid] = kk;
            float k2 = kk * kk;
#pragma unroll
            for (int off = 32; off > 0; off >>= 1) k2 += __shfl_xor(k2, off, 64);
            if (tid == 0) sc[1] = sqrtf(k2);
        } else if (tid == 64) {   // beta = softplus
            float zb = wred[12] + wred[13] + wred[14] + wred[15];
            sc[0] = logf(1.f + __expf(zb));
        }
        __syncthreads();
        const float beta = sc[0], knorm = sc[1];

        // fused num + ||mem_n||^2 pass: thread = mem row
        float num = 0.f, nr2 = 0.f;
        {
            const float4* mrow = (const float4*)(memA + tid * MEMPAD);
            const float4* k4p  = (const float4*)kv;
#pragma unroll
            for (int i = 0; i < 16; ++i) {
                float4 m4 = mrow[i], k4 = k4p[i];
                num += m4.x * k4.x + m4.y * k4.y + m4.z * k4.z + m4.w * k4.w;
                nr2 += m4.x * m4.x + m4.y * m4.y + m4.z * m4.z + m4.w * m4.w;
            }
        }
        float den = fmaxf(sqrtf(nr2) * knorm, 1e-8f);
        float s   = beta * (num / den);
        // per-wave max+sumexp, then combine
        float wm = s;
#pragma unroll
        for (int off = 32; off > 0; off >>= 1) wm = fmaxf(wm, __shfl_xor(wm, off, 64));
        float ev = __expf(s - wm);
        float wsum = ev;
#pragma unroll
        for (int off = 32; off > 0; off >>= 1) wsum += __shfl_xor(wsum, off, 64);
        if (lane == 0) { wred[wid] = wm; wred[8 + wid] = wsum; }
        __syncthreads();
        float gm = fmaxf(fmaxf(wred[0], wred[1]), fmaxf(wred[2], wred[3]));
        float gsum = wred[8]  * __expf(wred[0] - gm) + wred[9]  * __expf(wred[1] - gm)
                   + wred[10] * __expf(wred[2] - gm) + wred[11] * __expf(wred[3] - gm);
        float w = __expf(s - gm) / gsum;
        wwts[tid] = w;
        __syncthreads();

        // fused update + read pass (quad mapping: 4 rows x 16 col-f4 per iter)
        {
            const int lm = lane & 15, q = lane >> 4;
            float4 k4 = ((const float4*)kv)[lm];
            float r0 = 0.f, r1 = 0.f, r2 = 0.f, r3 = 0.f;
#pragma unroll
            for (int i = 0; i < 16; ++i) {
                int n = wid * 64 + i * 4 + q;
                float wn = wwts[n];
                float4* mp = (float4*)(memA + n * MEMPAD + 4 * lm);
                float4 m4 = *mp;
                m4.x += wn * k4.x; m4.y += wn * k4.y; m4.z += wn * k4.z; m4.w += wn * k4.w;
                *mp = m4;
                r0 += wn * m4.x; r1 += wn * m4.y; r2 += wn * m4.z; r3 += wn * m4.w;
            }
            r0 += __shfl_xor(r0, 16, 64); r0 += __shfl_xor(r0, 32, 64);
            r1 += __shfl_xor(r1, 16, 64); r1 += __shfl_xor(r1, 32, 64);
            r2 += __shfl_xor(r2, 16, 64); r2 += __shfl_xor(r2, 32, 64);
            r3 += __shfl_xor(r3, 16, 64); r3 += __shfl_xor(r3, 32, 64);
            if (q == 0) {
                rp[wid * 64 + 4 * lm + 0] = r0;
                rp[wid * 64 + 4 * lm + 1] = r1;
                rp[wid * 64 + 4 * lm + 2] = r2;
                rp[wid * 64 + 4 * lm + 3] = r3;
            }
        }
        __syncthreads();
        if (tid < 64) {
            float rd = rp[tid] + rp[64 + tid] + rp[128 + tid] + rp[192 + tid];
            hrF[tid] = rd;                                   // r(t) for next-step GEMV
            RsF[(size_t)(t * BATCH + b) * 64 + tid] = rd;    // epilogue-only
        }
        __syncthreads();
    }
}

// ---------------- epilogue: ys = Hs@Wpre + Rs@Wro_eff + b_pre ; loss partials ----------------
__global__ void dnc_epilogue(char* __restrict__ ws, void* __restrict__ outv) {
    __shared__ float hs8[8][256];
    __shared__ float rs8[8][64];
    __shared__ float lacc;
    const float* HsF   = (const float*)(ws + WS_HS);
    const float* RsF   = (const float*)(ws + WS_RS);
    const float* WktF  = (const float*)(ws + WS_WKT);
    const float* WreF  = (const float*)(ws + WS_WROEFF);
    const float* WpreF = (const float*)(ws + WS_WPREF);
    const float* bpreF = (const float*)(ws + WS_BPREF);
    float* lossacc = (float*)(ws + WS_LOSS);
    const int bf = *(const int*)(ws + WS_FLAG);
    const int tid = threadIdx.x;
    const size_t r0 = (size_t)blockIdx.x * 8;
    if (tid == 0) lacc = 0.f;
    for (int i = tid; i < 8 * 256; i += 256) hs8[i >> 8][i & 255] = HsF[r0 * 256 + i];
    for (int i = tid; i < 8 * 64; i += 256)  rs8[i >> 6][i & 63]  = RsF[r0 * 64 + i];
    __syncthreads();
    // ys
    {
        const int rl = tid >> 5, c0 = (tid & 31) * 4;
        float a0 = bpreF[c0], a1 = bpreF[c0 + 1], a2 = bpreF[c0 + 2], a3 = bpreF[c0 + 3];
        for (int k = 0; k < 256; ++k) {
            float hv = hs8[rl][k];
            float4 w4 = *(const float4*)(WpreF + k * 128 + c0);
            a0 += hv * w4.x; a1 += hv * w4.y; a2 += hv * w4.z; a3 += hv * w4.w;
        }
        for (int m = 0; m < 64; ++m) {
            float rv = rs8[rl][m];
            float4 w4 = *(const float4*)(WreF + m * 128 + c0);
            a0 += rv * w4.x; a1 += rv * w4.y; a2 += rv * w4.z; a3 += rv * w4.w;
        }
        size_t o = (r0 + rl) * 128 + c0;
        if (bf) {
            u16* out = (u16*)outv;
            out[o] = f2b(a0); out[o + 1] = f2b(a1); out[o + 2] = f2b(a2); out[o + 3] = f2b(a3);
        } else {
            float* out = (float*)outv;
            out[o] = a0; out[o + 1] = a1; out[o + 2] = a2; out[o + 3] = a3;
        }
    }
    // loss: sum (h @ (Wkey - Wteach))^2
    {
        const int rl = tid >> 5, m0 = (tid & 31) * 2;
        float d0 = 0.f, d1 = 0.f;
        for (int k = 0; k < 256; ++k) {
            float hv = hs8[rl][k];
            d0 += hv * WktF[k * 64 + m0];
            d1 += hv * WktF[k * 64 + m0 + 1];
        }
        float p = d0 * d0 + d1 * d1;
#pragma unroll
        for (int off = 32; off > 0; off >>= 1) p += __shfl_xor(p, off, 64);
        if ((tid & 63) == 0) atomicAdd(&lacc, p);
        __syncthreads();
        if (tid == 0) atomicAdd(lossacc, lacc);
    }
}

__global__ void dnc_loss_fin(const char* __restrict__ ws, void* __restrict__ outv) {
    if (threadIdx.x == 0 && blockIdx.x == 0) {
        float l = *(const float*)(ws + WS_LOSS) * (1.f / 2048.f);
        if (*(const int*)(ws + WS_FLAG)) ((u16*)outv)[524288] = f2b(l);
        else                             ((float*)outv)[524288] = l;
    }
}

// ---------------- launch ----------------
extern "C" void kernel_launch(void* const* d_in, const int* in_sizes, int n_in,
                              void* d_out, int out_size, void* d_ws, size_t ws_size,
                              hipStream_t stream) {
    char* ws = (char*)d_ws;
    hipMemsetAsync(d_ws, 0, WS_ZSET, stream);   // loss acc, dtype flag
    dnc_probe<<<1, 256, 0, stream>>>((const u16*)d_in[0], ws);
    dnc_normalize<<<512, 256, 0, stream>>>(d_in[0], d_in[1], d_in[2], d_in[3], d_in[4],
                                           d_in[5], d_in[6], d_in[7], d_in[8], d_in[9], ws);
    (void)hipFuncSetAttribute((const void*)dnc_prologue,
                              hipFuncAttributeMaxDynamicSharedMemorySize, 128 * 129 * 4);
    dnc_prologue<<<280, 256, 128 * 129 * 4, stream>>>(ws);
    dnc_pack<<<320, 256, 0, stream>>>(ws);
    (void)hipFuncSetAttribute((const void*)dnc_main,
                              hipFuncAttributeMaxDynamicSharedMemorySize, LDS_TOTAL);
    dnc_main<<<32, 256, LDS_TOTAL, stream>>>(ws);
    dnc_epilogue<<<512, 256, 0, stream>>>(ws, d_out);
    dnc_loss_fin<<<1, 64, 0, stream>>>(ws, d_out);
}

// Round 10
// 1301.344 us; speedup vs baseline: 1.7576x; 1.7576x over previous
//
#include <hip/hip_runtime.h>

// ---------------- types / helpers ----------------
typedef unsigned short u16;
typedef unsigned int u32;
typedef unsigned long long u64;
typedef short short8 __attribute__((ext_vector_type(8)));
typedef float f32x4 __attribute__((ext_vector_type(4)));

__device__ __forceinline__ float b2f(u16 u) {
    unsigned x = ((unsigned)u) << 16;
    return __builtin_bit_cast(float, x);
}
__device__ __forceinline__ u16 f2b(float f) {
    unsigned u = __builtin_bit_cast(unsigned, f);
    u += 0x7FFFu + ((u >> 16) & 1u);   // RNE
    return (u16)(u >> 16);
}
__device__ __forceinline__ float sigm(float x) { return 1.f / (1.f + __expf(-x)); }
__device__ __forceinline__ float tanh_(float x) { return 1.f - 2.f / (__expf(2.f * x) + 1.f); }

__device__ __forceinline__ u64 lda(const u64* p) {
    return __hip_atomic_load(p, __ATOMIC_RELAXED, __HIP_MEMORY_SCOPE_AGENT);
}
__device__ __forceinline__ void sta(u64* p, u64 v) {
    __hip_atomic_store(p, v, __ATOMIC_RELAXED, __HIP_MEMORY_SCOPE_AGENT);
}

// ---------------- problem constants ----------------
#define T_STEPS 128
#define BATCH   32
#define KHR     320
#define PADK    328      // hr_lds row pad (bf16 elems); u32 stride 164
#define MEMPAD  68       // mem row stride in floats
#define WKPAD   264      // wkeyT row pad (bf16 elems)

// ---------------- workspace layout (bytes) ----------------
#define WS_LOSS     128
#define WS_FLAG     160
// tagged exchange buffers. Chunk = 16B = {tag,w0 | w1,tag} as two u64 halves.
// hT[2][32 batch][32 wg][2 chunk]  = 2*32*32*2*16 = 65536
// rT[2][32 wg][16 chunk]           = 2*32*16*16   = 16384
#define WS_HT       1280
#define WS_RT       66816
#define WS_ZSET     83200                     // memset range end (tags must start 0)
// normalized fp32 inputs
#define WS_XSF      83968                     // 524288 f32
#define WS_MEM0F    2181120                   // 524288 f32
#define WS_WLF      4278272                   // 655360 f32
#define WS_BLF      6899712                   // 1024 f32
#define WS_WPREF    6903808                   // 32768 f32
#define WS_BPREF    7034880                   // 128 f32
#define WS_WKEYF    7035392                   // 16384 f32
#define WS_WBETAF   7100928                   // 256 f32
#define WS_WTEACHF  7101952                   // 16384 f32
#define WS_WROF     7167488                   // 32768 f32
// derived
#define WS_XW       7298560                   // f32 [4096][1024] = 16777216
#define WS_WREFF    24075776                  // f32 [64][1024]   = 262144
#define WS_WKT      24337920                  // f32 [256][64]    = 65536
#define WS_WROEFF   24403456                  // f32 [64][128]    = 32768
#define WS_HS       24436224                  // f32 [4096][256]  = 4194304
#define WS_RS       28630528                  // f32 [4096][64]   = 1048576  (end ~28.3 MiB)

// ---------------- LDS layout (bytes) ----------------
#define HR_OFF   0         // u16 [32][328]            20992
#define WF_OFF   20992     // u16 [10][4][32][8]       20480
#define WK_OFF   41472     // u16 [64][264]            33792
#define MEM_OFF  75264     // f32 [256][68]            69632
#define Z_OFF    144896    // f32 [32][36]             4608
#define C_OFF    149504    // f32 [32][8]              1024
#define KV_OFF   151552    // f32 [64]                 256
#define WW_OFF   151808    // f32 [256]                1024
#define KP_OFF   152832    // f32 [4][64]              1024
#define RP_OFF   153856    // f32 [4][64]              1024
#define BR_OFF   154880    // f32 [16]
#define WR_OFF   154944    // f32 [16]
#define SC_OFF   155008    // f32 [16]
#define WB_OFF   155072    // f32 [256]                1024
#define HST_OFF  156096    // u16 [256]                512
#define RST_OFF  156608    // u16 [64]                 128
#define LDS_TOTAL 156736

// ---------------- dtype probe: f32 vs bf16 ----------------
__global__ void dnc_probe(const u16* __restrict__ xs_u16, char* __restrict__ ws) {
    __shared__ int cnt;
    if (threadIdx.x == 0) cnt = 0;
    __syncthreads();
    int c = 0;
    for (int i = threadIdx.x; i < 1024; i += 256) {
        int e = (xs_u16[i] >> 7) & 0xFF;
        if (e >= 96 && e <= 135) c++;
    }
    atomicAdd(&cnt, c);
    __syncthreads();
    if (threadIdx.x == 0) *(int*)(ws + WS_FLAG) = (cnt > 820) ? 1 : 0;   // 1 = bf16
}

// ---------------- normalize all inputs to fp32 in ws ----------------
__global__ void dnc_normalize(const void* s0, const void* s1, const void* s2, const void* s3,
                              const void* s4, const void* s5, const void* s6, const void* s7,
                              const void* s8, const void* s9, char* __restrict__ ws) {
    const void* srcs[10] = {s0, s1, s2, s3, s4, s5, s6, s7, s8, s9};
    const int sizes[10] = {524288, 524288, 655360, 1024, 32768, 128, 16384, 256, 16384, 32768};
    const int bases[10] = {WS_XSF, WS_MEM0F, WS_WLF, WS_BLF, WS_WPREF, WS_BPREF,
                           WS_WKEYF, WS_WBETAF, WS_WTEACHF, WS_WROF};
    const int bf = *(const int*)(ws + WS_FLAG);
    const int gt = blockIdx.x * 256 + threadIdx.x, gs = gridDim.x * 256;
    for (int s = 0; s < 10; ++s) {
        float* dst = (float*)(ws + bases[s]);
        const int n = sizes[s];
        if (bf) {
            const u16* p = (const u16*)srcs[s];
            for (int i = gt; i < n; i += gs) dst[i] = b2f(p[i]);
        } else {
            const float* p = (const float*)srcs[s];
            for (int i = gt; i < n; i += gs) dst[i] = p[i];
        }
    }
}

// ---------------- prologue: xW 2D-blocked GEMM + weight folds (fp32) ----------------
__global__ void dnc_prologue(char* __restrict__ ws) {
    extern __shared__ float xls[];   // [128][129]
    const float* XSF     = (const float*)(ws + WS_XSF);
    const float* WLF     = (const float*)(ws + WS_WLF);
    const float* BLF     = (const float*)(ws + WS_BLF);
    const float* WKEYF   = (const float*)(ws + WS_WKEYF);
    const float* WTEACHF = (const float*)(ws + WS_WTEACHF);
    const float* WROF    = (const float*)(ws + WS_WROF);
    float* xW  = (float*)(ws + WS_XW);
    float* WrE = (float*)(ws + WS_WREFF);
    float* Wkt = (float*)(ws + WS_WKT);
    float* Wre = (float*)(ws + WS_WROEFF);
    const int wg = blockIdx.x, tid = threadIdx.x;
    if (wg < 256) {
        const int rb = wg >> 3, cb = wg & 7;
        const float4* xsrc = (const float4*)(XSF + (size_t)rb * 16384);
        for (int i = tid; i < 4096; i += 256) {
            float4 v = xsrc[i];
            int row = i >> 5, c4 = (i & 31) * 4;
            float* d = xls + row * 129 + c4;
            d[0] = v.x; d[1] = v.y; d[2] = v.z; d[3] = v.w;
        }
        __syncthreads();
        const int tr = tid >> 4, tc = tid & 15;
        const int c0 = cb * 128 + tc * 8;
        float acc[8][8];
#pragma unroll
        for (int rr = 0; rr < 8; ++rr)
#pragma unroll
            for (int cc = 0; cc < 8; ++cc) acc[rr][cc] = BLF[c0 + cc];
        for (int k = 0; k < 128; ++k) {
            float4 wA = *(const float4*)(WLF + (size_t)k * 1024 + c0);
            float4 wB = *(const float4*)(WLF + (size_t)k * 1024 + c0 + 4);
            float w[8] = {wA.x, wA.y, wA.z, wA.w, wB.x, wB.y, wB.z, wB.w};
#pragma unroll
            for (int rr = 0; rr < 8; ++rr) {
                float xv = xls[(tr * 8 + rr) * 129 + k];
#pragma unroll
                for (int cc = 0; cc < 8; ++cc) acc[rr][cc] += xv * w[cc];
            }
        }
#pragma unroll
        for (int rr = 0; rr < 8; ++rr) {
            size_t o = (size_t)(rb * 128 + tr * 8 + rr) * 1024 + c0;
            *(float4*)(xW + o)     = make_float4(acc[rr][0], acc[rr][1], acc[rr][2], acc[rr][3]);
            *(float4*)(xW + o + 4) = make_float4(acc[rr][4], acc[rr][5], acc[rr][6], acc[rr][7]);
        }
    } else if (wg < 320) {
        const int m = wg - 256;
        const int c = tid * 4;
#pragma unroll
        for (int e = 0; e < 4; ++e) {
            float s = 0.f;
#pragma unroll
            for (int rr = 0; rr < 4; ++rr) s += WLF[(size_t)(128 + 4 * m + rr) * 1024 + c + e];
            WrE[m * 1024 + c + e] = s;
        }
    } else if (wg < 336) {
        const int i = (wg - 320) * 1024 + tid * 4;
#pragma unroll
        for (int e = 0; e < 4; ++e) Wkt[i + e] = WKEYF[i + e] - WTEACHF[i + e];
    } else if (wg < 344) {
        const int i = (wg - 336) * 1024 + tid * 4;
#pragma unroll
        for (int e = 0; e < 4; ++e) {
            int m = (i + e) >> 7, c = (i + e) & 127;
            float s = 0.f;
#pragma unroll
            for (int rr = 0; rr < 4; ++rr) s += WROF[(4 * m + rr) * 128 + c];
            Wre[i + e] = s;
        }
    }
}

// ---------------- main persistent kernel: 32 wgs, tagged dataflow, NO barriers ----------------
// Exchange chunk = 16B = two tagged u64 halves {tag,w0},{w1,tag}; reader accepts iff both
// tags == step tag. Double-buffered by parity. Skew safety: wg X can overwrite buffer p
// (written at steps t, t+2) only after X passes its r-poll(t+1), which requires EVERY wg's
// r(t+1), which each wg publishes only after consuming h(t)/r(t) — so no reader can still
// be waiting on buffer p's step-t contents when step-t+2 data lands.
__global__ __launch_bounds__(256, 1) void dnc_main(char* __restrict__ ws) {
    extern __shared__ char smem[];
    u16*   hr_lds = (u16*)(smem + HR_OFF);
    u16*   wfrag  = (u16*)(smem + WF_OFF);
    u16*   wkeyT  = (u16*)(smem + WK_OFF);
    float* memA   = (float*)(smem + MEM_OFF);
    float* z_lds  = (float*)(smem + Z_OFF);
    float* c_lds  = (float*)(smem + C_OFF);
    float* kv     = (float*)(smem + KV_OFF);
    float* wwts   = (float*)(smem + WW_OFF);
    float* kpart  = (float*)(smem + KP_OFF);
    float* rp     = (float*)(smem + RP_OFF);
    float* bred   = (float*)(smem + BR_OFF);
    float* wred   = (float*)(smem + WR_OFF);
    float* sc     = (float*)(smem + SC_OFF);
    float* wbF    = (float*)(smem + WB_OFF);
    u16*   hstage = (u16*)(smem + HST_OFF);
    u16*   rstage = (u16*)(smem + RST_OFF);

    const int tid  = threadIdx.x;
    const int wg   = blockIdx.x;     // col-slice id AND batch id (0..31)
    const int lane = tid & 63;
    const int wid  = tid >> 6;

    u64* hT = (u64*)(ws + WS_HT);    // [2][32 b][32 w][2 c][2 u64]
    u64* rT = (u64*)(ws + WS_RT);    // [2][32 w][16 c][2 u64]
    const float* xWF     = (const float*)(ws + WS_XW);
    const float* WrEffF  = (const float*)(ws + WS_WREFF);
    const float* WLF     = (const float*)(ws + WS_WLF);
    const float* WKEYF   = (const float*)(ws + WS_WKEYF);
    const float* WBETAF  = (const float*)(ws + WS_WBETAF);
    const float* MEM0F   = (const float*)(ws + WS_MEM0F);
    float* HsF = (float*)(ws + WS_HS);
    float* RsF = (float*)(ws + WS_RS);

    // ---- one-time LDS init ----
    for (int i = tid; i < 32 * PADK; i += 256) hr_lds[i] = 0;   // h(-1)=0, r(-1)=0
    for (int idx = tid; idx < 10240; idx += 256) {
        int k = idx >> 5, c = idx & 31;
        int kt = k >> 5, q = (k >> 3) & 3, j = k & 7;
        int gcol = (c >> 3) * 256 + wg * 8 + (c & 7);
        float v = (k < 64) ? WrEffF[k * 1024 + gcol]
                           : WLF[(size_t)(384 + (k - 64)) * 1024 + gcol];
        wfrag[((kt * 4 + q) * 32 + c) * 8 + j] = f2b(v);
    }
    for (int i = tid; i < 256 * 64; i += 256) {   // wkeyT[m][k] = Wkey[k][m] (bf16)
        int k = i >> 6, m = i & 63;
        wkeyT[m * WKPAD + k] = f2b(WKEYF[i]);
    }
    wbF[tid]   = WBETAF[tid];
    c_lds[tid] = 0.f;
    for (int i = tid; i < 256 * 64; i += 256) {   // mem state fp32
        int n = i >> 6, m = i & 63;
        memA[n * MEMPAD + m] = MEM0F[wg * 16384 + i];
    }
    __syncthreads();

    const int bt = wid & 1, ct = wid >> 1;   // MFMA tile assignment
    const int fm = lane & 15, fq = lane >> 4;
    const int pb = tid >> 3, pu = tid & 7;   // batch / slice-unit for staging & pointwise

    // xW gates for t=0; h@Wh accumulator for t=0 is 0 (h(-1)=0)
    float xg0, xg1, xg2, xg3;
    {
        const size_t xb = (size_t)pb * 1024 + wg * 8 + pu;
        xg0 = xWF[xb]; xg1 = xWF[xb + 256]; xg2 = xWF[xb + 512]; xg3 = xWF[xb + 768];
    }
    f32x4 hWacc = {0.f, 0.f, 0.f, 0.f};

    for (int t = 0; t < T_STEPS; ++t) {
        // ================= phase A =================
        // poll r(t-1): buffer (t+1)&1, tag t. Thread (pb,pu) needs chunks 2pu,2pu+1 of wg pb.
        {
            const u64* rch = rT + (size_t)((((t + 1) & 1) * 32 + pb) * 16 + 2 * pu) * 2;
            const u32 want = (u32)t;
            u64 v0, v1, v2, v3;
            long guard = 0;
            for (;;) {
                v0 = lda(rch); v1 = lda(rch + 1); v2 = lda(rch + 2); v3 = lda(rch + 3);
                bool ok = ((u32)v0 == want) && ((u32)(v1 >> 32) == want) &&
                          ((u32)v2 == want) && ((u32)(v3 >> 32) == want);
                if (ok) break;
                if (++guard > 100000L) break;   // bail instead of hanging
            }
            u32* dst = (u32*)hr_lds + pb * 164 + 4 * pu;
            dst[0] = (u32)(v0 >> 32); dst[1] = (u32)v1;
            dst[2] = (u32)(v2 >> 32); dst[3] = (u32)v3;
        }
        __syncthreads();

        // rW MFMA (kt=0,1) accumulating onto carried h@Wh
        f32x4 acc = hWacc;
#pragma unroll
        for (int kt = 0; kt < 2; ++kt) {
            short8 a = *(const short8*)(hr_lds + (bt * 16 + fm) * PADK + kt * 32 + fq * 8);
            short8 b = *(const short8*)(wfrag + ((kt * 4 + fq) * 32 + ct * 16 + fm) * 8);
            acc = __builtin_amdgcn_mfma_f32_16x16x32_bf16(a, b, acc, 0, 0, 0);
        }
#pragma unroll
        for (int r = 0; r < 4; ++r) {
            int bb = bt * 16 + fq * 4 + r;        // C/D: row = quad*4+reg
            int cc = ct * 16 + fm;                //       col = lane&15
            z_lds[bb * 36 + cc] = acc[r];
        }
        __syncthreads();

        // LSTM pointwise for hidden units [8*wg, 8*wg+8), all batches
        {
            float iv = z_lds[pb * 36 + pu]      + xg0;
            float fv = z_lds[pb * 36 + 8 + pu]  + xg1;
            float gv = z_lds[pb * 36 + 16 + pu] + xg2;
            float ov = z_lds[pb * 36 + 24 + pu] + xg3;
            float co = c_lds[pb * 8 + pu];
            float cn = sigm(fv) * co + sigm(iv) * tanh_(gv);
            float hn = sigm(ov) * tanh_(cn);
            c_lds[pb * 8 + pu] = cn;
            hstage[pb * 8 + pu] = f2b(hn);
            HsF[(size_t)(t * BATCH + pb) * 256 + wg * 8 + pu] = hn;   // epilogue-only
        }
        __syncthreads();
        // publish h(t): tid<64 -> chunk (b=tid>>1, c=tid&1), buffer t&1, tag t+1
        if (tid < 64) {
            const int b = tid >> 1, c = tid & 1;
            const u32* hs32 = (const u32*)hstage;
            u32 w0 = hs32[b * 4 + 2 * c], w1 = hs32[b * 4 + 2 * c + 1];
            u64* dstc = hT + (size_t)((((t & 1) * 32 + b) * 32 + wg) * 2 + c) * 2;
            const u64 tag = (u64)(u32)(t + 1);
            sta(dstc,     ((u64)w0 << 32) | tag);
            sta(dstc + 1, (tag << 32) | w1);
        }

        // ================= phase B =================
        // h-independent work first (overlaps publish->visibility): ||mem_n||^2
        float nr2 = 0.f;
        {
            const float4* mrow = (const float4*)(memA + tid * MEMPAD);
#pragma unroll
            for (int i = 0; i < 16; ++i) {
                float4 m4 = mrow[i];
                nr2 += m4.x * m4.x + m4.y * m4.y + m4.z * m4.z + m4.w * m4.w;
            }
        }
        // poll h(t): thread (pb,pu) needs 8 contiguous chunks (wgs 4pu..4pu+3)
        {
            const u64* hch = hT + (size_t)((((t & 1) * 32 + pb) * 32 + 4 * pu) * 2) * 2;
            const u32 want = (u32)(t + 1);
            u64 v[16];
            long guard = 0;
            for (;;) {
#pragma unroll
                for (int i = 0; i < 16; ++i) v[i] = lda(hch + i);
                bool ok = true;
#pragma unroll
                for (int i = 0; i < 8; ++i)
                    ok = ok && ((u32)v[2 * i] == want) && ((u32)(v[2 * i + 1] >> 32) == want);
                if (ok) break;
                if (++guard > 100000L) break;   // bail instead of hanging
            }
            u32* dst = (u32*)hr_lds + pb * 164 + 32 + 16 * pu;
#pragma unroll
            for (int i = 0; i < 8; ++i) {
                dst[2 * i]     = (u32)(v[2 * i] >> 32);
                dst[2 * i + 1] = (u32)v[2 * i + 1];
            }
        }
        __syncthreads();

        // xW gates for t+1 (plain cached loads; drained by next step's poll waits)
        {
            int tn = (t + 1 < T_STEPS) ? t + 1 : 127;
            const size_t xb = (size_t)(tn * BATCH + pb) * 1024 + wg * 8 + pu;
            xg0 = xWF[xb]; xg1 = xWF[xb + 256]; xg2 = xWF[xb + 512]; xg3 = xWF[xb + 768];
        }

        // hW MFMA (kt=2..9) -> fresh accumulator carried to phase A of t+1
        {
            f32x4 hz = {0.f, 0.f, 0.f, 0.f};
#pragma unroll
            for (int kt = 2; kt < 10; ++kt) {
                short8 a = *(const short8*)(hr_lds + (bt * 16 + fm) * PADK + kt * 32 + fq * 8);
                short8 b = *(const short8*)(wfrag + ((kt * 4 + fq) * 32 + ct * 16 + fm) * 8);
                hz = __builtin_amdgcn_mfma_f32_16x16x32_bf16(a, b, hz, 0, 0, 0);
            }
            hWacc = hz;
        }

        // M phase: this wg owns batch b = wg; h_b in hr_lds[wg]
        const u16* hrow = hr_lds + wg * PADK + 64;
        {
            float a = 0.f;
#pragma unroll
            for (int i = 0; i < 8; ++i) {
                short8 w8 = *(const short8*)(wkeyT + lane * WKPAD + wid * 64 + i * 8);
                short8 h8 = *(const short8*)(hrow + wid * 64 + i * 8);
#pragma unroll
                for (int e = 0; e < 8; ++e)
                    a += b2f((u16)h8[e]) * b2f((u16)w8[e]);
            }
            kpart[wid * 64 + lane] = a;
        }
        {
            float bp = b2f(hrow[tid]) * wbF[tid];
#pragma unroll
            for (int off = 32; off > 0; off >>= 1) bp += __shfl_xor(bp, off, 64);
            if (lane == 0) bred[wid] = bp;
        }
        __syncthreads();
        if (tid < 64) {   // finalize k, ||k||
            float kk = kpart[tid] + kpart[64 + tid] + kpart[128 + tid] + kpart[192 + tid];
            kv[tid] = kk;
            float k2 = kk * kk;
#pragma unroll
            for (int off = 32; off > 0; off >>= 1) k2 += __shfl_xor(k2, off, 64);
            if (tid == 0) sc[1] = sqrtf(k2);
        } else if (tid == 64) {   // beta = softplus
            float zb = bred[0] + bred[1] + bred[2] + bred[3];
            sc[0] = logf(1.f + __expf(zb));
        }
        __syncthreads();
        const float beta = sc[0], knorm = sc[1];

        // num pass (nr2 precomputed): thread = mem row
        float num = 0.f;
        {
            const float4* mrow = (const float4*)(memA + tid * MEMPAD);
            const float4* k4p  = (const float4*)kv;
#pragma unroll
            for (int i = 0; i < 16; ++i) {
                float4 m4 = mrow[i], k4 = k4p[i];
                num += m4.x * k4.x + m4.y * k4.y + m4.z * k4.z + m4.w * k4.w;
            }
        }
        float den = fmaxf(sqrtf(nr2) * knorm, 1e-8f);
        float s   = beta * (num / den);
        // per-wave max+sumexp, then combine
        float wm = s;
#pragma unroll
        for (int off = 32; off > 0; off >>= 1) wm = fmaxf(wm, __shfl_xor(wm, off, 64));
        float ev = __expf(s - wm);
        float wsum = ev;
#pragma unroll
        for (int off = 32; off > 0; off >>= 1) wsum += __shfl_xor(wsum, off, 64);
        if (lane == 0) { wred[wid] = wm; wred[8 + wid] = wsum; }
        __syncthreads();
        float gm = fmaxf(fmaxf(wred[0], wred[1]), fmaxf(wred[2], wred[3]));
        float gsum = wred[8]  * __expf(wred[0] - gm) + wred[9]  * __expf(wred[1] - gm)
                   + wred[10] * __expf(wred[2] - gm) + wred[11] * __expf(wred[3] - gm);
        float w = __expf(s - gm) / gsum;
        wwts[tid] = w;
        __syncthreads();

        // fused update + read pass (quad mapping: 4 rows x 16 col-f4 per iter)
        {
            const int lm = lane & 15, q = lane >> 4;
            float4 k4 = ((const float4*)kv)[lm];
            float r0 = 0.f, r1 = 0.f, r2 = 0.f, r3 = 0.f;
#pragma unroll
            for (int i = 0; i < 16; ++i) {
                int n = wid * 64 + i * 4 + q;
                float wn = wwts[n];
                float4* mp = (float4*)(memA + n * MEMPAD + 4 * lm);
                float4 m4 = *mp;
                m4.x += wn * k4.x; m4.y += wn * k4.y; m4.z += wn * k4.z; m4.w += wn * k4.w;
                *mp = m4;
                r0 += wn * m4.x; r1 += wn * m4.y; r2 += wn * m4.z; r3 += wn * m4.w;
            }
            r0 += __shfl_xor(r0, 16, 64); r0 += __shfl_xor(r0, 32, 64);
            r1 += __shfl_xor(r1, 16, 64); r1 += __shfl_xor(r1, 32, 64);
            r2 += __shfl_xor(r2, 16, 64); r2 += __shfl_xor(r2, 32, 64);
            r3 += __shfl_xor(r3, 16, 64); r3 += __shfl_xor(r3, 32, 64);
            if (q == 0) {
                rp[wid * 64 + 4 * lm + 0] = r0;
                rp[wid * 64 + 4 * lm + 1] = r1;
                rp[wid * 64 + 4 * lm + 2] = r2;
                rp[wid * 64 + 4 * lm + 3] = r3;
            }
        }
        __syncthreads();
        if (tid < 64) {
            float rd = rp[tid] + rp[64 + tid] + rp[128 + tid] + rp[192 + tid];
            rstage[tid] = f2b(rd);
            RsF[(size_t)(t * BATCH + wg) * 64 + tid] = rd;   // epilogue-only
        }
        __syncthreads();
        // publish r(t): tid<16 -> chunk c=tid, buffer t&1, tag t+1
        if (tid < 16) {
            const u32* rs32 = (const u32*)rstage;
            u32 w0 = rs32[2 * tid], w1 = rs32[2 * tid + 1];
            u64* dstc = rT + (size_t)(((t & 1) * 32 + wg) * 16 + tid) * 2;
            const u64 tag = (u64)(u32)(t + 1);
            sta(dstc,     ((u64)w0 << 32) | tag);
            sta(dstc + 1, (tag << 32) | w1);
        }
    }
}

// ---------------- epilogue: ys = Hs@Wpre + Rs@Wro_eff + b_pre ; loss partials ----------------
__global__ void dnc_epilogue(char* __restrict__ ws, void* __restrict__ outv) {
    __shared__ float hs8[8][256];
    __shared__ float rs8[8][64];
    __shared__ float lacc;
    const float* HsF   = (const float*)(ws + WS_HS);
    const float* RsF   = (const float*)(ws + WS_RS);
    const float* WktF  = (const float*)(ws + WS_WKT);
    const float* WreF  = (const float*)(ws + WS_WROEFF);
    const float* WpreF = (const float*)(ws + WS_WPREF);
    const float* bpreF = (const float*)(ws + WS_BPREF);
    float* lossacc = (float*)(ws + WS_LOSS);
    const int bf = *(const int*)(ws + WS_FLAG);
    const int tid = threadIdx.x;
    const size_t r0 = (size_t)blockIdx.x * 8;
    if (tid == 0) lacc = 0.f;
    for (int i = tid; i < 8 * 256; i += 256) hs8[i >> 8][i & 255] = HsF[r0 * 256 + i];
    for (int i = tid; i < 8 * 64; i += 256)  rs8[i >> 6][i & 63]  = RsF[r0 * 64 + i];
    __syncthreads();
    // ys
    {
        const int rl = tid >> 5, c0 = (tid & 31) * 4;
        float a0 = bpreF[c0], a1 = bpreF[c0 + 1], a2 = bpreF[c0 + 2], a3 = bpreF[c0 + 3];
        for (int k = 0; k < 256; ++k) {
            float hv = hs8[rl][k];
            float4 w4 = *(const float4*)(WpreF + k * 128 + c0);
            a0 += hv * w4.x; a1 += hv * w4.y; a2 += hv * w4.z; a3 += hv * w4.w;
        }
        for (int m = 0; m < 64; ++m) {
            float rv = rs8[rl][m];
            float4 w4 = *(const float4*)(WreF + m * 128 + c0);
            a0 += rv * w4.x; a1 += rv * w4.y; a2 += rv * w4.z; a3 += rv * w4.w;
        }
        size_t o = (r0 + rl) * 128 + c0;
        if (bf) {
            u16* out = (u16*)outv;
            out[o] = f2b(a0); out[o + 1] = f2b(a1); out[o + 2] = f2b(a2); out[o + 3] = f2b(a3);
        } else {
            float* out = (float*)outv;
            out[o] = a0; out[o + 1] = a1; out[o + 2] = a2; out[o + 3] = a3;
        }
    }
    // loss: sum (h @ (Wkey - Wteach))^2
    {
        const int rl = tid >> 5, m0 = (tid & 31) * 2;
        float d0 = 0.f, d1 = 0.f;
        for (int k = 0; k < 256; ++k) {
            float hv = hs8[rl][k];
            d0 += hv * WktF[k * 64 + m0];
            d1 += hv * WktF[k * 64 + m0 + 1];
        }
        float p = d0 * d0 + d1 * d1;
#pragma unroll
        for (int off = 32; off > 0; off >>= 1) p += __shfl_xor(p, off, 64);
        if ((tid & 63) == 0) atomicAdd(&lacc, p);
        __syncthreads();
        if (tid == 0) atomicAdd(lossacc, lacc);
    }
}

__global__ void dnc_loss_fin(const char* __restrict__ ws, void* __restrict__ outv) {
    if (threadIdx.x == 0 && blockIdx.x == 0) {
        float l = *(const float*)(ws + WS_LOSS) * (1.f / 2048.f);
        if (*(const int*)(ws + WS_FLAG)) ((u16*)outv)[524288] = f2b(l);
        else                             ((float*)outv)[524288] = l;
    }
}

// ---------------- launch ----------------
extern "C" void kernel_launch(void* const* d_in, const int* in_sizes, int n_in,
                              void* d_out, int out_size, void* d_ws, size_t ws_size,
                              hipStream_t stream) {
    char* ws = (char*)d_ws;
    hipMemsetAsync(d_ws, 0, WS_ZSET, stream);   // loss, dtype flag, hT/rT tags
    dnc_probe<<<1, 256, 0, stream>>>((const u16*)d_in[0], ws);
    dnc_normalize<<<512, 256, 0, stream>>>(d_in[0], d_in[1], d_in[2], d_in[3], d_in[4],
                                           d_in[5], d_in[6], d_in[7], d_in[8], d_in[9], ws);
    (void)hipFuncSetAttribute((const void*)dnc_prologue,
                              hipFuncAttributeMaxDynamicSharedMemorySize, 128 * 129 * 4);
    dnc_prologue<<<344, 256, 128 * 129 * 4, stream>>>(ws);
    (void)hipFuncSetAttribute((const void*)dnc_main,
                              hipFuncAttributeMaxDynamicSharedMemorySize, LDS_TOTAL);
    dnc_main<<<32, 256, LDS_TOTAL, stream>>>(ws);
    dnc_epilogue<<<512, 256, 0, stream>>>(ws, d_out);
    dnc_loss_fin<<<1, 64, 0, stream>>>(ws, d_out);
}

// Round 11
// 1075.525 us; speedup vs baseline: 2.1266x; 1.2100x over previous
//
#include <hip/hip_runtime.h>

// ---------------- types / helpers ----------------
typedef unsigned short u16;
typedef unsigned int u32;
typedef unsigned long long u64;
typedef short short8 __attribute__((ext_vector_type(8)));
typedef float f32x4 __attribute__((ext_vector_type(4)));

__device__ __forceinline__ float b2f(u16 u) {
    unsigned x = ((unsigned)u) << 16;
    return __builtin_bit_cast(float, x);
}
__device__ __forceinline__ u16 f2b(float f) {
    unsigned u = __builtin_bit_cast(unsigned, f);
    u += 0x7FFFu + ((u >> 16) & 1u);   // RNE
    return (u16)(u >> 16);
}
__device__ __forceinline__ float sigm(float x) { return 1.f / (1.f + __expf(-x)); }
__device__ __forceinline__ float tanh_(float x) { return 1.f - 2.f / (__expf(2.f * x) + 1.f); }

__device__ __forceinline__ u64 lda(const u64* p) {
    return __hip_atomic_load(p, __ATOMIC_RELAXED, __HIP_MEMORY_SCOPE_AGENT);
}
__device__ __forceinline__ void sta(u64* p, u64 v) {
    __hip_atomic_store(p, v, __ATOMIC_RELAXED, __HIP_MEMORY_SCOPE_AGENT);
}
__device__ __forceinline__ unsigned ld_flag(const unsigned* p) {
    return __hip_atomic_load(p, __ATOMIC_RELAXED, __HIP_MEMORY_SCOPE_AGENT);
}
__device__ __forceinline__ void st_flag(unsigned* p, unsigned v) {
    __hip_atomic_store(p, v, __ATOMIC_RELAXED, __HIP_MEMORY_SCOPE_AGENT);
}
// agent-coherent 16B load (sc0 sc1), waitcnt fused
__device__ __forceinline__ void ld16x4_issue(const void* p0, const void* p1, const void* p2,
                                             const void* p3, uint4& a, uint4& b, uint4& c, uint4& d) {
    asm volatile(
        "global_load_dwordx4 %0, %4, off sc0 sc1\n\t"
        "global_load_dwordx4 %1, %5, off sc0 sc1\n\t"
        "global_load_dwordx4 %2, %6, off sc0 sc1\n\t"
        "global_load_dwordx4 %3, %7, off sc0 sc1"
        : "=v"(a), "=v"(b), "=v"(c), "=v"(d)
        : "v"(p0), "v"(p1), "v"(p2), "v"(p3) : "memory");
}
__device__ __forceinline__ void wait_vm0() {
    asm volatile("s_waitcnt vmcnt(0)" ::: "memory");
}
__device__ __forceinline__ void st16(void* p, uint4 v) {
    u64 lo = ((u64)v.y << 32) | (u64)v.x;
    u64 hi = ((u64)v.w << 32) | (u64)v.z;
    __hip_atomic_store((u64*)p,     lo, __ATOMIC_RELAXED, __HIP_MEMORY_SCOPE_AGENT);
    __hip_atomic_store((u64*)p + 1, hi, __ATOMIC_RELAXED, __HIP_MEMORY_SCOPE_AGENT);
}

// ---------------- problem constants ----------------
#define T_STEPS 128
#define BATCH   32
#define KHR     320
#define PADK    328      // hr_lds row pad (bf16 elems); u32 stride 164
#define MEMPAD  68       // mem row stride in floats
#define WKPAD   264      // wkeyT row pad (bf16 elems)

// ---------------- workspace layout (bytes) ----------------
#define WS_BAR      0                         // u32 [32] barrier flags (h barrier)
#define WS_LOSS     128
#define WS_FLAG     160
#define WS_RT       192                       // tagged r: [2][32 wg][16 chunk][2 u64] = 16384
#define WS_HRG      16576                     // u16 [32][320] = 20480 (h region at +64)
#define WS_ZSET     41088                     // memset range end
// normalized fp32 inputs
#define WS_XSF      41216                     // 524288 f32
#define WS_MEM0F    2138368                   // 524288 f32
#define WS_WLF      4235520                   // 655360 f32
#define WS_BLF      6856960                   // 1024 f32
#define WS_WPREF    6861056                   // 32768 f32
#define WS_BPREF    6992128                   // 128 f32
#define WS_WKEYF    6992640                   // 16384 f32
#define WS_WBETAF   7058176                   // 256 f32
#define WS_WTEACHF  7059200                   // 16384 f32
#define WS_WROF     7124736                   // 32768 f32
// derived
#define WS_XW       7255808                   // f32 [4096][1024] = 16777216
#define WS_WREFF    24033024                  // f32 [64][1024]   = 262144
#define WS_WKT      24295168                  // f32 [256][64]    = 65536
#define WS_WROEFF   24360704                  // f32 [64][128]    = 32768
#define WS_HS       24393472                  // f32 [4096][256]  = 4194304
#define WS_RS       28587776                  // f32 [4096][64]   = 1048576

// ---------------- LDS layout (bytes) ----------------
#define HR_OFF   0         // u16 [32][328]            20992
#define WF_OFF   20992     // u16 [10][4][32][8]       20480
#define WK_OFF   41472     // u16 [64][264]            33792
#define MEM_OFF  75264     // f32 [256][68]            69632
#define Z_OFF    144896    // f32 [32][36]             4608
#define C_OFF    149504    // f32 [32][8]              1024
#define KV_OFF   151552    // f32 [64]                 256
#define WW_OFF   151808    // f32 [256]                1024
#define KP_OFF   152832    // f32 [4][64]              1024
#define RP_OFF   153856    // f32 [4][64]              1024
#define BR_OFF   154880    // f32 [16]
#define WR_OFF   154944    // f32 [16]
#define SC_OFF   155008    // f32 [16]
#define WB_OFF   155072    // f32 [256]                1024
#define HST_OFF  156096    // u16 [256]                512
#define RST_OFF  156608    // u16 [64]                 128
#define LDS_TOTAL 156736

// ---------------- flag-array grid barrier (32 wgs) — h exchange only ----------------
__device__ __forceinline__ void gridbar(unsigned* flags, unsigned phase, int rank) {
    __syncthreads();
    if (threadIdx.x < 64) {
        if (threadIdx.x == 0) st_flag(flags + rank, phase);
        long guard = 0;
        for (;;) {
            unsigned v = ld_flag(flags + (threadIdx.x & 31));
            if (__ballot(v < phase) == 0ull) break;
            if (++guard > 1000000L) break;   // bail instead of hanging
        }
    }
    __syncthreads();
}

// ---------------- dtype probe: f32 vs bf16 ----------------
__global__ void dnc_probe(const u16* __restrict__ xs_u16, char* __restrict__ ws) {
    __shared__ int cnt;
    if (threadIdx.x == 0) cnt = 0;
    __syncthreads();
    int c = 0;
    for (int i = threadIdx.x; i < 1024; i += 256) {
        int e = (xs_u16[i] >> 7) & 0xFF;
        if (e >= 96 && e <= 135) c++;
    }
    atomicAdd(&cnt, c);
    __syncthreads();
    if (threadIdx.x == 0) *(int*)(ws + WS_FLAG) = (cnt > 820) ? 1 : 0;   // 1 = bf16
}

// ---------------- normalize all inputs to fp32 in ws ----------------
__global__ void dnc_normalize(const void* s0, const void* s1, const void* s2, const void* s3,
                              const void* s4, const void* s5, const void* s6, const void* s7,
                              const void* s8, const void* s9, char* __restrict__ ws) {
    const void* srcs[10] = {s0, s1, s2, s3, s4, s5, s6, s7, s8, s9};
    const int sizes[10] = {524288, 524288, 655360, 1024, 32768, 128, 16384, 256, 16384, 32768};
    const int bases[10] = {WS_XSF, WS_MEM0F, WS_WLF, WS_BLF, WS_WPREF, WS_BPREF,
                           WS_WKEYF, WS_WBETAF, WS_WTEACHF, WS_WROF};
    const int bf = *(const int*)(ws + WS_FLAG);
    const int gt = blockIdx.x * 256 + threadIdx.x, gs = gridDim.x * 256;
    for (int s = 0; s < 10; ++s) {
        float* dst = (float*)(ws + bases[s]);
        const int n = sizes[s];
        if (bf) {
            const u16* p = (const u16*)srcs[s];
            for (int i = gt; i < n; i += gs) dst[i] = b2f(p[i]);
        } else {
            const float* p = (const float*)srcs[s];
            for (int i = gt; i < n; i += gs) dst[i] = p[i];
        }
    }
}

// ---------------- prologue: xW 2D-blocked GEMM + weight folds (fp32) ----------------
__global__ void dnc_prologue(char* __restrict__ ws) {
    extern __shared__ float xls[];   // [128][129]
    const float* XSF     = (const float*)(ws + WS_XSF);
    const float* WLF     = (const float*)(ws + WS_WLF);
    const float* BLF     = (const float*)(ws + WS_BLF);
    const float* WKEYF   = (const float*)(ws + WS_WKEYF);
    const float* WTEACHF = (const float*)(ws + WS_WTEACHF);
    const float* WROF    = (const float*)(ws + WS_WROF);
    float* xW  = (float*)(ws + WS_XW);
    float* WrE = (float*)(ws + WS_WREFF);
    float* Wkt = (float*)(ws + WS_WKT);
    float* Wre = (float*)(ws + WS_WROEFF);
    const int wg = blockIdx.x, tid = threadIdx.x;
    if (wg < 256) {
        const int rb = wg >> 3, cb = wg & 7;
        const float4* xsrc = (const float4*)(XSF + (size_t)rb * 16384);
        for (int i = tid; i < 4096; i += 256) {
            float4 v = xsrc[i];
            int row = i >> 5, c4 = (i & 31) * 4;
            float* d = xls + row * 129 + c4;
            d[0] = v.x; d[1] = v.y; d[2] = v.z; d[3] = v.w;
        }
        __syncthreads();
        const int tr = tid >> 4, tc = tid & 15;
        const int c0 = cb * 128 + tc * 8;
        float acc[8][8];
#pragma unroll
        for (int rr = 0; rr < 8; ++rr)
#pragma unroll
            for (int cc = 0; cc < 8; ++cc) acc[rr][cc] = BLF[c0 + cc];
        for (int k = 0; k < 128; ++k) {
            float4 wA = *(const float4*)(WLF + (size_t)k * 1024 + c0);
            float4 wB = *(const float4*)(WLF + (size_t)k * 1024 + c0 + 4);
            float w[8] = {wA.x, wA.y, wA.z, wA.w, wB.x, wB.y, wB.z, wB.w};
#pragma unroll
            for (int rr = 0; rr < 8; ++rr) {
                float xv = xls[(tr * 8 + rr) * 129 + k];
#pragma unroll
                for (int cc = 0; cc < 8; ++cc) acc[rr][cc] += xv * w[cc];
            }
        }
#pragma unroll
        for (int rr = 0; rr < 8; ++rr) {
            size_t o = (size_t)(rb * 128 + tr * 8 + rr) * 1024 + c0;
            *(float4*)(xW + o)     = make_float4(acc[rr][0], acc[rr][1], acc[rr][2], acc[rr][3]);
            *(float4*)(xW + o + 4) = make_float4(acc[rr][4], acc[rr][5], acc[rr][6], acc[rr][7]);
        }
    } else if (wg < 320) {
        const int m = wg - 256;
        const int c = tid * 4;
#pragma unroll
        for (int e = 0; e < 4; ++e) {
            float s = 0.f;
#pragma unroll
            for (int rr = 0; rr < 4; ++rr) s += WLF[(size_t)(128 + 4 * m + rr) * 1024 + c + e];
            WrE[m * 1024 + c + e] = s;
        }
    } else if (wg < 336) {
        const int i = (wg - 320) * 1024 + tid * 4;
#pragma unroll
        for (int e = 0; e < 4; ++e) Wkt[i + e] = WKEYF[i + e] - WTEACHF[i + e];
    } else if (wg < 344) {
        const int i = (wg - 336) * 1024 + tid * 4;
#pragma unroll
        for (int e = 0; e < 4; ++e) {
            int m = (i + e) >> 7, c = (i + e) & 127;
            float s = 0.f;
#pragma unroll
            for (int rr = 0; rr < 4; ++rr) s += WROF[(4 * m + rr) * 128 + c];
            Wre[i + e] = s;
        }
    }
}

// ---------------- main persistent kernel: 32 wgs ----------------
// 1 barrier/step (h exchange). r exchange is tagged dataflow (R10 scheme),
// published BEFORE the mem update via r = w@mem_old + ||w||^2 k, so the
// consumer poll at phase-A top has a long publish shadow (update pass +
// pointwise) and hits first-try. WAR safety: rT double-buffered by parity;
// barrier1 bounds skew to <1 step, so r(t-2)'s readers (in A(t-1), before
// barrier1(t-1)) are long gone when the owner (past barrier1(t)) overwrites.
__global__ __launch_bounds__(256, 1) void dnc_main(char* __restrict__ ws) {
    extern __shared__ char smem[];
    u16*   hr_lds = (u16*)(smem + HR_OFF);
    u16*   wfrag  = (u16*)(smem + WF_OFF);
    u16*   wkeyT  = (u16*)(smem + WK_OFF);
    float* memA   = (float*)(smem + MEM_OFF);
    float* z_lds  = (float*)(smem + Z_OFF);
    float* c_lds  = (float*)(smem + C_OFF);
    float* kv     = (float*)(smem + KV_OFF);
    float* wwts   = (float*)(smem + WW_OFF);
    float* kpart  = (float*)(smem + KP_OFF);
    float* rp     = (float*)(smem + RP_OFF);
    float* bred   = (float*)(smem + BR_OFF);
    float* wred   = (float*)(smem + WR_OFF);
    float* sc     = (float*)(smem + SC_OFF);
    float* wbF    = (float*)(smem + WB_OFF);
    u16*   hstage = (u16*)(smem + HST_OFF);
    u16*   rstage = (u16*)(smem + RST_OFF);

    const int tid  = threadIdx.x;
    const int wg   = blockIdx.x;     // col-slice id AND batch id (0..31)
    const int lane = tid & 63;
    const int wid  = tid >> 6;

    unsigned* flags = (unsigned*)(ws + WS_BAR);
    u64* rT         = (u64*)(ws + WS_RT);      // [2][32 wg][16 chunk][2 u64]
    u16* hrg        = (u16*)(ws + WS_HRG);     // [32][320] bf16 (h at +64)
    const float* xWF     = (const float*)(ws + WS_XW);
    const float* WrEffF  = (const float*)(ws + WS_WREFF);
    const float* WLF     = (const float*)(ws + WS_WLF);
    const float* WKEYF   = (const float*)(ws + WS_WKEYF);
    const float* WBETAF  = (const float*)(ws + WS_WBETAF);
    const float* MEM0F   = (const float*)(ws + WS_MEM0F);
    float* HsF = (float*)(ws + WS_HS);
    float* RsF = (float*)(ws + WS_RS);

    // ---- one-time LDS init ----
    for (int i = tid; i < 32 * PADK; i += 256) hr_lds[i] = 0;   // h(-1)=0, r(-1)=0
    for (int idx = tid; idx < 10240; idx += 256) {
        int k = idx >> 5, c = idx & 31;
        int kt = k >> 5, q = (k >> 3) & 3, j = k & 7;
        int gcol = (c >> 3) * 256 + wg * 8 + (c & 7);
        float v = (k < 64) ? WrEffF[k * 1024 + gcol]
                           : WLF[(size_t)(384 + (k - 64)) * 1024 + gcol];
        wfrag[((kt * 4 + q) * 32 + c) * 8 + j] = f2b(v);
    }
    for (int i = tid; i < 256 * 64; i += 256) {   // wkeyT[m][k] = Wkey[k][m] (bf16)
        int k = i >> 6, m = i & 63;
        wkeyT[m * WKPAD + k] = f2b(WKEYF[i]);
    }
    wbF[tid]   = WBETAF[tid];
    c_lds[tid] = 0.f;
    for (int i = tid; i < 256 * 64; i += 256) {   // mem state fp32
        int n = i >> 6, m = i & 63;
        memA[n * MEMPAD + m] = MEM0F[wg * 16384 + i];
    }
    __syncthreads();

    const int bt = wid & 1, ct = wid >> 1;   // MFMA tile assignment
    const int fm = lane & 15, fq = lane >> 4;
    const int pb = tid >> 3, pu = tid & 7;   // batch / slice-unit for staging & pointwise

    // xW gates for t=0; h@Wh accumulator for t=0 is 0 (h(-1)=0)
    float xg0, xg1, xg2, xg3;
    {
        const size_t xb = (size_t)pb * 1024 + wg * 8 + pu;
        xg0 = xWF[xb]; xg1 = xWF[xb + 256]; xg2 = xWF[xb + 512]; xg3 = xWF[xb + 768];
    }
    f32x4 hWacc = {0.f, 0.f, 0.f, 0.f};

    for (int t = 0; t < T_STEPS; ++t) {
        // ================= phase A =================
        // poll r(t-1): buffer (t+1)&1, tag t (R10 scheme). Long publish shadow -> first-try.
        {
            const u64* rch = rT + (size_t)((((t + 1) & 1) * 32 + pb) * 16 + 2 * pu) * 2;
            const u32 want = (u32)t;
            u64 v0, v1, v2, v3;
            long guard = 0;
            for (;;) {
                v0 = lda(rch); v1 = lda(rch + 1); v2 = lda(rch + 2); v3 = lda(rch + 3);
                bool ok = ((u32)v0 == want) && ((u32)(v1 >> 32) == want) &&
                          ((u32)v2 == want) && ((u32)(v3 >> 32) == want);
                if (ok) break;
                if (++guard > 200000L) break;   // bail instead of hanging
            }
            u32* dst = (u32*)hr_lds + pb * 164 + 4 * pu;
            dst[0] = (u32)(v0 >> 32); dst[1] = (u32)v1;
            dst[2] = (u32)(v2 >> 32); dst[3] = (u32)v3;
        }
        __syncthreads();

        // rW MFMA (kt=0,1) accumulating onto carried h@Wh
        f32x4 acc = hWacc;
#pragma unroll
        for (int kt = 0; kt < 2; ++kt) {
            short8 a = *(const short8*)(hr_lds + (bt * 16 + fm) * PADK + kt * 32 + fq * 8);
            short8 b = *(const short8*)(wfrag + ((kt * 4 + fq) * 32 + ct * 16 + fm) * 8);
            acc = __builtin_amdgcn_mfma_f32_16x16x32_bf16(a, b, acc, 0, 0, 0);
        }
#pragma unroll
        for (int r = 0; r < 4; ++r) {
            int bb = bt * 16 + fq * 4 + r;        // C/D: row = quad*4+reg
            int cc = ct * 16 + fm;                //       col = lane&15
            z_lds[bb * 36 + cc] = acc[r];
        }
        __syncthreads();

        // LSTM pointwise for hidden units [8*wg, 8*wg+8), all batches
        {
            float iv = z_lds[pb * 36 + pu]      + xg0;
            float fv = z_lds[pb * 36 + 8 + pu]  + xg1;
            float gv = z_lds[pb * 36 + 16 + pu] + xg2;
            float ov = z_lds[pb * 36 + 24 + pu] + xg3;
            float co = c_lds[pb * 8 + pu];
            float cn = sigm(fv) * co + sigm(iv) * tanh_(gv);
            float hn = sigm(ov) * tanh_(cn);
            c_lds[pb * 8 + pu] = cn;
            hstage[pb * 8 + pu] = f2b(hn);
            HsF[(size_t)(t * BATCH + pb) * 256 + wg * 8 + pu] = hn;   // epilogue-only
        }
        __syncthreads();
        if (tid < 32) {   // packed h store: 16B per batch row
            uint4 hv = *(const uint4*)(hstage + tid * 8);
            st16(hrg + tid * KHR + 64 + wg * 8, hv);
        }
        gridbar(flags, (unsigned)(t + 1), wg);

        // ================= phase B =================
        // issue h(t) prefetch (16 KB total), no waitcnt yet
        uint4 ha, hb4, hc, hd;
        {
            const u16* src = hrg + pb * KHR + 64 + pu * 32;
            ld16x4_issue(src, src + 8, src + 16, src + 24, ha, hb4, hc, hd);
        }
        // xW gates for t+1 (plain cached loads, drain at wait_vm0)
        {
            int tn = (t + 1 < T_STEPS) ? t + 1 : 127;
            const size_t xb = (size_t)(tn * BATCH + pb) * 1024 + wg * 8 + pu;
            xg0 = xWF[xb]; xg1 = xWF[xb + 256]; xg2 = xWF[xb + 512]; xg3 = xWF[xb + 768];
        }
        // h-independent work while loads fly: ||mem_n||^2 (mem_old for this step)
        float nr2 = 0.f;
        {
            const float4* mrow = (const float4*)(memA + tid * MEMPAD);
#pragma unroll
            for (int i = 0; i < 16; ++i) {
                float4 m4 = mrow[i];
                nr2 += m4.x * m4.x + m4.y * m4.y + m4.z * m4.z + m4.w * m4.w;
            }
        }
        wait_vm0();
        {
            u16* dst = hr_lds + pb * PADK + 64 + pu * 32;
            *(uint4*)(dst)      = ha;
            *(uint4*)(dst + 8)  = hb4;
            *(uint4*)(dst + 16) = hc;
            *(uint4*)(dst + 24) = hd;
        }
        __syncthreads();

        // hW MFMA (kt=2..9) -> fresh accumulator carried to phase A of t+1
        {
            f32x4 hz = {0.f, 0.f, 0.f, 0.f};
#pragma unroll
            for (int kt = 2; kt < 10; ++kt) {
                short8 a = *(const short8*)(hr_lds + (bt * 16 + fm) * PADK + kt * 32 + fq * 8);
                short8 b = *(const short8*)(wfrag + ((kt * 4 + fq) * 32 + ct * 16 + fm) * 8);
                hz = __builtin_amdgcn_mfma_f32_16x16x32_bf16(a, b, hz, 0, 0, 0);
            }
            hWacc = hz;
        }

        // M phase: this wg owns batch b = wg; h_b in hr_lds[wg]
        const u16* hrow = hr_lds + wg * PADK + 64;
        {
            float a = 0.f;
#pragma unroll
            for (int i = 0; i < 8; ++i) {
                short8 w8 = *(const short8*)(wkeyT + lane * WKPAD + wid * 64 + i * 8);
                short8 h8 = *(const short8*)(hrow + wid * 64 + i * 8);
#pragma unroll
                for (int e = 0; e < 8; ++e)
                    a += b2f((u16)h8[e]) * b2f((u16)w8[e]);
            }
            kpart[wid * 64 + lane] = a;
        }
        {
            float bp = b2f(hrow[tid]) * wbF[tid];
#pragma unroll
            for (int off = 32; off > 0; off >>= 1) bp += __shfl_xor(bp, off, 64);
            if (lane == 0) bred[wid] = bp;
        }
        __syncthreads();
        if (tid < 64) {   // finalize k, ||k||
            float kk = kpart[tid] + kpart[64 + tid] + kpart[128 + tid] + kpart[192 + tid];
            kv[tid] = kk;
            float k2 = kk * kk;
#pragma unroll
            for (int off = 32; off > 0; off >>= 1) k2 += __shfl_xor(k2, off, 64);
            if (tid == 0) sc[1] = sqrtf(k2);
        } else if (tid == 64) {   // beta = softplus
            float zb = bred[0] + bred[1] + bred[2] + bred[3];
            sc[0] = logf(1.f + __expf(zb));
        }
        __syncthreads();
        const float beta = sc[0], knorm = sc[1];

        // num pass (nr2 precomputed): thread = mem row, on mem_old
        float num = 0.f;
        {
            const float4* mrow = (const float4*)(memA + tid * MEMPAD);
            const float4* k4p  = (const float4*)kv;
#pragma unroll
            for (int i = 0; i < 16; ++i) {
                float4 m4 = mrow[i], k4 = k4p[i];
                num += m4.x * k4.x + m4.y * k4.y + m4.z * k4.z + m4.w * k4.w;
            }
        }
        float den = fmaxf(sqrtf(nr2) * knorm, 1e-8f);
        float s   = beta * (num / den);
        // per-wave max+sumexp, then combine
        float wm = s;
#pragma unroll
        for (int off = 32; off > 0; off >>= 1) wm = fmaxf(wm, __shfl_xor(wm, off, 64));
        float ev = __expf(s - wm);
        float wsum = ev;
#pragma unroll
        for (int off = 32; off > 0; off >>= 1) wsum += __shfl_xor(wsum, off, 64);
        if (lane == 0) { wred[wid] = wm; wred[8 + wid] = wsum; }
        __syncthreads();
        float gm = fmaxf(fmaxf(wred[0], wred[1]), fmaxf(wred[2], wred[3]));
        float gsum = wred[8]  * __expf(wred[0] - gm) + wred[9]  * __expf(wred[1] - gm)
                   + wred[10] * __expf(wred[2] - gm) + wred[11] * __expf(wred[3] - gm);
        float w = __expf(s - gm) / gsum;
        wwts[tid] = w;
        // ||w||^2 partials (for r = w@mem_old + ||w||^2 k)
        {
            float w2 = w * w;
#pragma unroll
            for (int off = 32; off > 0; off >>= 1) w2 += __shfl_xor(w2, off, 64);
            if (lane == 0) bred[wid] = w2;
        }
        __syncthreads();
        const float wsq = bred[0] + bred[1] + bred[2] + bred[3];

        // READ pass on mem_old (no update yet): quad mapping
        {
            const int lm = lane & 15, q = lane >> 4;
            float r0 = 0.f, r1 = 0.f, r2 = 0.f, r3 = 0.f;
#pragma unroll
            for (int i = 0; i < 16; ++i) {
                int n = wid * 64 + i * 4 + q;
                float wn = wwts[n];
                float4 m4 = *(const float4*)(memA + n * MEMPAD + 4 * lm);
                r0 += wn * m4.x; r1 += wn * m4.y; r2 += wn * m4.z; r3 += wn * m4.w;
            }
            r0 += __shfl_xor(r0, 16, 64); r0 += __shfl_xor(r0, 32, 64);
            r1 += __shfl_xor(r1, 16, 64); r1 += __shfl_xor(r1, 32, 64);
            r2 += __shfl_xor(r2, 16, 64); r2 += __shfl_xor(r2, 32, 64);
            r3 += __shfl_xor(r3, 16, 64); r3 += __shfl_xor(r3, 32, 64);
            if (q == 0) {
                rp[wid * 64 + 4 * lm + 0] = r0;
                rp[wid * 64 + 4 * lm + 1] = r1;
                rp[wid * 64 + 4 * lm + 2] = r2;
                rp[wid * 64 + 4 * lm + 3] = r3;
            }
        }
        __syncthreads();
        if (tid < 64) {
            float rd = rp[tid] + rp[64 + tid] + rp[128 + tid] + rp[192 + tid]
                     + wsq * kv[tid];
            rstage[tid] = f2b(rd);
            RsF[(size_t)(t * BATCH + wg) * 64 + tid] = rd;   // epilogue-only
        }
        __syncthreads();
        // publish r(t) EARLY (tagged, buffer t&1, tag t+1) — before mem update
        if (tid < 16) {
            const u32* rs32 = (const u32*)rstage;
            u32 w0 = rs32[2 * tid], w1 = rs32[2 * tid + 1];
            u64* dstc = rT + (size_t)(((t & 1) * 32 + wg) * 16 + tid) * 2;
            const u64 tag = (u64)(u32)(t + 1);
            sta(dstc,     ((u64)w0 << 32) | tag);
            sta(dstc + 1, (tag << 32) | w1);
        }
        // mem UPDATE pass — off the critical path (covers r's flight to the LLC)
        {
            const int lm = lane & 15, q = lane >> 4;
            float4 k4 = ((const float4*)kv)[lm];
#pragma unroll
            for (int i = 0; i < 16; ++i) {
                int n = wid * 64 + i * 4 + q;
                float wn = wwts[n];
                float4* mp = (float4*)(memA + n * MEMPAD + 4 * lm);
                float4 m4 = *mp;
                m4.x += wn * k4.x; m4.y += wn * k4.y; m4.z += wn * k4.z; m4.w += wn * k4.w;
                *mp = m4;
            }
        }
        // no barrier2: next step's r-poll + barrier1 bound the skew
    }
}

// ---------------- epilogue: ys = Hs@Wpre + Rs@Wro_eff + b_pre ; loss partials ----------------
__global__ void dnc_epilogue(char* __restrict__ ws, void* __restrict__ outv) {
    __shared__ float hs8[8][256];
    __shared__ float rs8[8][64];
    __shared__ float lacc;
    const float* HsF   = (const float*)(ws + WS_HS);
    const float* RsF   = (const float*)(ws + WS_RS);
    const float* WktF  = (const float*)(ws + WS_WKT);
    const float* WreF  = (const float*)(ws + WS_WROEFF);
    const float* WpreF = (const float*)(ws + WS_WPREF);
    const float* bpreF = (const float*)(ws + WS_BPREF);
    float* lossacc = (float*)(ws + WS_LOSS);
    const int bf = *(const int*)(ws + WS_FLAG);
    const int tid = threadIdx.x;
    const size_t r0 = (size_t)blockIdx.x * 8;
    if (tid == 0) lacc = 0.f;
    for (int i = tid; i < 8 * 256; i += 256) hs8[i >> 8][i & 255] = HsF[r0 * 256 + i];
    for (int i = tid; i < 8 * 64; i += 256)  rs8[i >> 6][i & 63]  = RsF[r0 * 64 + i];
    __syncthreads();
    // ys
    {
        const int rl = tid >> 5, c0 = (tid & 31) * 4;
        float a0 = bpreF[c0], a1 = bpreF[c0 + 1], a2 = bpreF[c0 + 2], a3 = bpreF[c0 + 3];
        for (int k = 0; k < 256; ++k) {
            float hv = hs8[rl][k];
            float4 w4 = *(const float4*)(WpreF + k * 128 + c0);
            a0 += hv * w4.x; a1 += hv * w4.y; a2 += hv * w4.z; a3 += hv * w4.w;
        }
        for (int m = 0; m < 64; ++m) {
            float rv = rs8[rl][m];
            float4 w4 = *(const float4*)(WreF + m * 128 + c0);
            a0 += rv * w4.x; a1 += rv * w4.y; a2 += rv * w4.z; a3 += rv * w4.w;
        }
        size_t o = (r0 + rl) * 128 + c0;
        if (bf) {
            u16* out = (u16*)outv;
            out[o] = f2b(a0); out[o + 1] = f2b(a1); out[o + 2] = f2b(a2); out[o + 3] = f2b(a3);
        } else {
            float* out = (float*)outv;
            out[o] = a0; out[o + 1] = a1; out[o + 2] = a2; out[o + 3] = a3;
        }
    }
    // loss: sum (h @ (Wkey - Wteach))^2
    {
        const int rl = tid >> 5, m0 = (tid & 31) * 2;
        float d0 = 0.f, d1 = 0.f;
        for (int k = 0; k < 256; ++k) {
            float hv = hs8[rl][k];
            d0 += hv * WktF[k * 64 + m0];
            d1 += hv * WktF[k * 64 + m0 + 1];
        }
        float p = d0 * d0 + d1 * d1;
#pragma unroll
        for (int off = 32; off > 0; off >>= 1) p += __shfl_xor(p, off, 64);
        if ((tid & 63) == 0) atomicAdd(&lacc, p);
        __syncthreads();
        if (tid == 0) atomicAdd(lossacc, lacc);
    }
}

__global__ void dnc_loss_fin(const char* __restrict__ ws, void* __restrict__ outv) {
    if (threadIdx.x == 0 && blockIdx.x == 0) {
        float l = *(const float*)(ws + WS_LOSS) * (1.f / 2048.f);
        if (*(const int*)(ws + WS_FLAG)) ((u16*)outv)[524288] = f2b(l);
        else                             ((float*)outv)[524288] = l;
    }
}

// ---------------- launch ----------------
extern "C" void kernel_launch(void* const* d_in, const int* in_sizes, int n_in,
                              void* d_out, int out_size, void* d_ws, size_t ws_size,
                              hipStream_t stream) {
    char* ws = (char*)d_ws;
    hipMemsetAsync(d_ws, 0, WS_ZSET, stream);   // flags, rT tags, loss, dtype flag, hrg
    dnc_probe<<<1, 256, 0, stream>>>((const u16*)d_in[0], ws);
    dnc_normalize<<<512, 256, 0, stream>>>(d_in[0], d_in[1], d_in[2], d_in[3], d_in[4],
                                           d_in[5], d_in[6], d_in[7], d_in[8], d_in[9], ws);
    (void)hipFuncSetAttribute((const void*)dnc_prologue,
                              hipFuncAttributeMaxDynamicSharedMemorySize, 128 * 129 * 4);
    dnc_prologue<<<344, 256, 128 * 129 * 4, stream>>>(ws);
    (void)hipFuncSetAttribute((const void*)dnc_main,
                              hipFuncAttributeMaxDynamicSharedMemorySize, LDS_TOTAL);
    dnc_main<<<32, 256, LDS_TOTAL, stream>>>(ws);
    dnc_epilogue<<<512, 256, 0, stream>>>(ws, d_out);
    dnc_loss_fin<<<1, 64, 0, stream>>>(ws, d_out);
}

// Round 12
// 1039.718 us; speedup vs baseline: 2.1999x; 1.0344x over previous
//
#include <hip/hip_runtime.h>

// ---------------- types / helpers ----------------
typedef unsigned short u16;
typedef unsigned int u32;
typedef unsigned long long u64;
typedef short short8 __attribute__((ext_vector_type(8)));
typedef float f32x4 __attribute__((ext_vector_type(4)));

__device__ __forceinline__ float b2f(u16 u) {
    unsigned x = ((unsigned)u) << 16;
    return __builtin_bit_cast(float, x);
}
__device__ __forceinline__ u16 f2b(float f) {
    unsigned u = __builtin_bit_cast(unsigned, f);
    u += 0x7FFFu + ((u >> 16) & 1u);   // RNE
    return (u16)(u >> 16);
}
__device__ __forceinline__ float sigm(float x) { return 1.f / (1.f + __expf(-x)); }
__device__ __forceinline__ float tanh_(float x) { return 1.f - 2.f / (__expf(2.f * x) + 1.f); }

__device__ __forceinline__ u64 lda(const u64* p) {
    return __hip_atomic_load(p, __ATOMIC_RELAXED, __HIP_MEMORY_SCOPE_AGENT);
}
__device__ __forceinline__ void sta(u64* p, u64 v) {
    __hip_atomic_store(p, v, __ATOMIC_RELAXED, __HIP_MEMORY_SCOPE_AGENT);
}
__device__ __forceinline__ unsigned ld_flag(const unsigned* p) {
    return __hip_atomic_load(p, __ATOMIC_RELAXED, __HIP_MEMORY_SCOPE_AGENT);
}
__device__ __forceinline__ void st_flag(unsigned* p, unsigned v) {
    __hip_atomic_store(p, v, __ATOMIC_RELAXED, __HIP_MEMORY_SCOPE_AGENT);
}
// agent-coherent 16B loads (sc0 sc1), issue-only; pair with wait_vm0()
__device__ __forceinline__ void ld16x4_issue(const void* p0, const void* p1, const void* p2,
                                             const void* p3, uint4& a, uint4& b, uint4& c, uint4& d) {
    asm volatile(
        "global_load_dwordx4 %0, %4, off sc0 sc1\n\t"
        "global_load_dwordx4 %1, %5, off sc0 sc1\n\t"
        "global_load_dwordx4 %2, %6, off sc0 sc1\n\t"
        "global_load_dwordx4 %3, %7, off sc0 sc1"
        : "=v"(a), "=v"(b), "=v"(c), "=v"(d)
        : "v"(p0), "v"(p1), "v"(p2), "v"(p3) : "memory");
}
__device__ __forceinline__ void wait_vm0() {
    asm volatile("s_waitcnt vmcnt(0)" ::: "memory");
}
__device__ __forceinline__ void st16(void* p, uint4 v) {
    u64 lo = ((u64)v.y << 32) | (u64)v.x;
    u64 hi = ((u64)v.w << 32) | (u64)v.z;
    __hip_atomic_store((u64*)p,     lo, __ATOMIC_RELAXED, __HIP_MEMORY_SCOPE_AGENT);
    __hip_atomic_store((u64*)p + 1, hi, __ATOMIC_RELAXED, __HIP_MEMORY_SCOPE_AGENT);
}

// ---------------- problem constants ----------------
#define T_STEPS 128
#define BATCH   32
#define KHR     320
#define PADK    328      // hr_lds row pad (bf16 elems); u32 stride 164
#define MEMPAD  68       // mem row stride in floats
#define WKPAD   264      // wkeyT row pad (bf16 elems)

// ---------------- workspace layout (bytes) ----------------
#define WS_BAR      0                         // u32 [32] barrier flags (h barrier)
#define WS_LOSS     128
#define WS_FLAG     160
#define WS_RT       192                       // tagged r: [2][32 wg][16 chunk][2 u64] = 16384
#define WS_HRG      16576                     // u16 [32][320] = 20480 (h region at +64)
#define WS_ZSET     41088                     // memset range end
// normalized fp32 inputs
#define WS_XSF      41216                     // 524288 f32
#define WS_MEM0F    2138368                   // 524288 f32
#define WS_WLF      4235520                   // 655360 f32
#define WS_BLF      6856960                   // 1024 f32
#define WS_WPREF    6861056                   // 32768 f32
#define WS_BPREF    6992128                   // 128 f32
#define WS_WKEYF    6992640                   // 16384 f32
#define WS_WBETAF   7058176                   // 256 f32
#define WS_WTEACHF  7059200                   // 16384 f32
#define WS_WROF     7124736                   // 32768 f32
// derived
#define WS_XW       7255808                   // f32 [4096][1024] = 16777216
#define WS_WREFF    24033024                  // f32 [64][1024]   = 262144
#define WS_WKT      24295168                  // f32 [256][64]    = 65536
#define WS_WROEFF   24360704                  // f32 [64][128]    = 32768
#define WS_HS       24393472                  // f32 [4096][256]  = 4194304
#define WS_RS       28587776                  // f32 [4096][64]   = 1048576

// ---------------- LDS layout (bytes) ----------------
#define HR_OFF   0         // u16 [32][328]            20992
#define WF_OFF   20992     // u16 [10][4][32][8]       20480
#define WK_OFF   41472     // u16 [64][264]            33792
#define MEM_OFF  75264     // f32 [256][68]            69632
#define Z_OFF    144896    // f32 [32][36]             4608
#define C_OFF    149504    // f32 [32][8]              1024
#define KV_OFF   151552    // f32 [64]                 256
#define KP_OFF   152832    // f32 [4][64]              1024
#define RP_OFF   153856    // f32 [4][64]              1024
#define BR_OFF   154880    // f32 [16]
#define WR_OFF   154944    // f32 [16]
#define SC_OFF   155008    // f32 [16]
#define WB_OFF   155072    // f32 [256]                1024
#define HST_OFF  156096    // u16 [256]                512
#define RST_OFF  156608    // u16 [64]                 128
#define LDS_TOTAL 156736

// ---------------- flag-array grid barrier (32 wgs) — h exchange only ----------------
__device__ __forceinline__ void gridbar(unsigned* flags, unsigned phase, int rank) {
    __syncthreads();
    if (threadIdx.x < 64) {
        if (threadIdx.x == 0) st_flag(flags + rank, phase);
        long guard = 0;
        for (;;) {
            unsigned v = ld_flag(flags + (threadIdx.x & 31));
            if (__ballot(v < phase) == 0ull) break;
            if (++guard > 1000000L) break;   // bail instead of hanging
            if (guard > 4) __builtin_amdgcn_s_sleep(1);
        }
    }
    __syncthreads();
}

// ---------------- normalize all inputs to fp32 in ws (dtype probe fused, per-block) ----------------
__global__ void dnc_normalize(const void* s0, const void* s1, const void* s2, const void* s3,
                              const void* s4, const void* s5, const void* s6, const void* s7,
                              const void* s8, const void* s9, char* __restrict__ ws) {
    __shared__ int cnt;
    if (threadIdx.x == 0) cnt = 0;
    __syncthreads();
    {   // deterministic local probe: every block computes the same flag
        const u16* xs_u16 = (const u16*)s0;
        int c = 0;
        for (int i = threadIdx.x; i < 1024; i += 256) {
            int e = (xs_u16[i] >> 7) & 0xFF;
            if (e >= 96 && e <= 135) c++;
        }
        atomicAdd(&cnt, c);
    }
    __syncthreads();
    const int bf = (cnt > 820) ? 1 : 0;   // 1 = bf16
    if (blockIdx.x == 0 && threadIdx.x == 0) *(int*)(ws + WS_FLAG) = bf;
    const void* srcs[10] = {s0, s1, s2, s3, s4, s5, s6, s7, s8, s9};
    const int sizes[10] = {524288, 524288, 655360, 1024, 32768, 128, 16384, 256, 16384, 32768};
    const int bases[10] = {WS_XSF, WS_MEM0F, WS_WLF, WS_BLF, WS_WPREF, WS_BPREF,
                           WS_WKEYF, WS_WBETAF, WS_WTEACHF, WS_WROF};
    const int gt = blockIdx.x * 256 + threadIdx.x, gs = gridDim.x * 256;
    for (int s = 0; s < 10; ++s) {
        float* dst = (float*)(ws + bases[s]);
        const int n = sizes[s];
        if (bf) {
            const u16* p = (const u16*)srcs[s];
            for (int i = gt; i < n; i += gs) dst[i] = b2f(p[i]);
        } else {
            const float* p = (const float*)srcs[s];
            for (int i = gt; i < n; i += gs) dst[i] = p[i];
        }
    }
}

// ---------------- prologue: xW 2D-blocked GEMM (512 wgs, 128x64 tiles) + weight folds ----------------
__global__ void dnc_prologue(char* __restrict__ ws) {
    extern __shared__ float xls[];   // [128][129]
    const float* XSF     = (const float*)(ws + WS_XSF);
    const float* WLF     = (const float*)(ws + WS_WLF);
    const float* BLF     = (const float*)(ws + WS_BLF);
    const float* WKEYF   = (const float*)(ws + WS_WKEYF);
    const float* WTEACHF = (const float*)(ws + WS_WTEACHF);
    const float* WROF    = (const float*)(ws + WS_WROF);
    float* xW  = (float*)(ws + WS_XW);
    float* WrE = (float*)(ws + WS_WREFF);
    float* Wkt = (float*)(ws + WS_WKT);
    float* Wre = (float*)(ws + WS_WROEFF);
    const int wg = blockIdx.x, tid = threadIdx.x;
    if (wg < 512) {
        const int rb = wg >> 4, cb = wg & 15;   // 32 row-blocks x 16 col-blocks
        const float4* xsrc = (const float4*)(XSF + (size_t)rb * 16384);
        for (int i = tid; i < 4096; i += 256) {
            float4 v = xsrc[i];
            int row = i >> 5, c4 = (i & 31) * 4;
            float* d = xls + row * 129 + c4;
            d[0] = v.x; d[1] = v.y; d[2] = v.z; d[3] = v.w;
        }
        __syncthreads();
        const int tr = tid >> 4, tc = tid & 15;
        const int c0 = cb * 64 + tc * 4;
        float acc[8][4];
#pragma unroll
        for (int rr = 0; rr < 8; ++rr) {
            acc[rr][0] = BLF[c0]; acc[rr][1] = BLF[c0 + 1];
            acc[rr][2] = BLF[c0 + 2]; acc[rr][3] = BLF[c0 + 3];
        }
        for (int k = 0; k < 128; ++k) {
            float4 w4 = *(const float4*)(WLF + (size_t)k * 1024 + c0);
#pragma unroll
            for (int rr = 0; rr < 8; ++rr) {
                float xv = xls[(tr * 8 + rr) * 129 + k];
                acc[rr][0] += xv * w4.x; acc[rr][1] += xv * w4.y;
                acc[rr][2] += xv * w4.z; acc[rr][3] += xv * w4.w;
            }
        }
#pragma unroll
        for (int rr = 0; rr < 8; ++rr) {
            size_t o = (size_t)(rb * 128 + tr * 8 + rr) * 1024 + c0;
            *(float4*)(xW + o) = make_float4(acc[rr][0], acc[rr][1], acc[rr][2], acc[rr][3]);
        }
    } else if (wg < 576) {
        const int m = wg - 512;
        const int c = tid * 4;
#pragma unroll
        for (int e = 0; e < 4; ++e) {
            float s = 0.f;
#pragma unroll
            for (int rr = 0; rr < 4; ++rr) s += WLF[(size_t)(128 + 4 * m + rr) * 1024 + c + e];
            WrE[m * 1024 + c + e] = s;
        }
    } else if (wg < 592) {
        const int i = (wg - 576) * 1024 + tid * 4;
#pragma unroll
        for (int e = 0; e < 4; ++e) Wkt[i + e] = WKEYF[i + e] - WTEACHF[i + e];
    } else if (wg < 600) {
        const int i = (wg - 592) * 1024 + tid * 4;
#pragma unroll
        for (int e = 0; e < 4; ++e) {
            int m = (i + e) >> 7, c = (i + e) & 127;
            float s = 0.f;
#pragma unroll
            for (int rr = 0; rr < 4; ++rr) s += WROF[(4 * m + rr) * 128 + c];
            Wre[i + e] = s;
        }
    }
}

// ---------------- main persistent kernel: 32 wgs ----------------
// 1 barrier/step (h). r is tagged dataflow published before the mem update
// (r = w@mem_old + ||w||^2 k), giving the consumer poll a full-update shadow.
// WAR safety: rT double-buffered by parity; barrier1 bounds skew <1 step.
__global__ __launch_bounds__(256, 1) void dnc_main(char* __restrict__ ws) {
    extern __shared__ char smem[];
    u16*   hr_lds = (u16*)(smem + HR_OFF);
    u16*   wfrag  = (u16*)(smem + WF_OFF);
    u16*   wkeyT  = (u16*)(smem + WK_OFF);
    float* memA   = (float*)(smem + MEM_OFF);
    float* z_lds  = (float*)(smem + Z_OFF);
    float* c_lds  = (float*)(smem + C_OFF);
    float* kv     = (float*)(smem + KV_OFF);
    float* kpart  = (float*)(smem + KP_OFF);
    float* rp     = (float*)(smem + RP_OFF);
    float* bred   = (float*)(smem + BR_OFF);
    float* wred   = (float*)(smem + WR_OFF);
    float* sc     = (float*)(smem + SC_OFF);
    float* wbF    = (float*)(smem + WB_OFF);
    u16*   hstage = (u16*)(smem + HST_OFF);
    u16*   rstage = (u16*)(smem + RST_OFF);

    const int tid  = threadIdx.x;
    const int wg   = blockIdx.x;     // col-slice id AND batch id (0..31)
    const int lane = tid & 63;
    const int wid  = tid >> 6;

    unsigned* flags = (unsigned*)(ws + WS_BAR);
    u64* rT         = (u64*)(ws + WS_RT);      // [2][32 wg][16 chunk][2 u64]
    u16* hrg        = (u16*)(ws + WS_HRG);     // [32][320] bf16 (h at +64)
    const float* xWF     = (const float*)(ws + WS_XW);
    const float* WrEffF  = (const float*)(ws + WS_WREFF);
    const float* WLF     = (const float*)(ws + WS_WLF);
    const float* WKEYF   = (const float*)(ws + WS_WKEYF);
    const float* WBETAF  = (const float*)(ws + WS_WBETAF);
    const float* MEM0F   = (const float*)(ws + WS_MEM0F);
    float* HsF = (float*)(ws + WS_HS);
    float* RsF = (float*)(ws + WS_RS);

    // ---- one-time LDS init ----
    for (int i = tid; i < 32 * PADK; i += 256) hr_lds[i] = 0;   // h(-1)=0, r(-1)=0
    for (int idx = tid; idx < 10240; idx += 256) {
        int k = idx >> 5, c = idx & 31;
        int kt = k >> 5, q = (k >> 3) & 3, j = k & 7;
        int gcol = (c >> 3) * 256 + wg * 8 + (c & 7);
        float v = (k < 64) ? WrEffF[k * 1024 + gcol]
                           : WLF[(size_t)(384 + (k - 64)) * 1024 + gcol];
        wfrag[((kt * 4 + q) * 32 + c) * 8 + j] = f2b(v);
    }
    for (int i = tid; i < 256 * 64; i += 256) {   // wkeyT[m][k] = Wkey[k][m] (bf16)
        int k = i >> 6, m = i & 63;
        wkeyT[m * WKPAD + k] = f2b(WKEYF[i]);
    }
    wbF[tid]   = WBETAF[tid];
    c_lds[tid] = 0.f;
    for (int i = tid; i < 256 * 64; i += 256) {   // mem state fp32
        int n = i >> 6, m = i & 63;
        memA[n * MEMPAD + m] = MEM0F[wg * 16384 + i];
    }
    __syncthreads();

    const int bt = wid & 1, ct = wid >> 1;   // MFMA tile assignment
    const int fm = lane & 15, fq = lane >> 4;
    const int pb = tid >> 3, pu = tid & 7;   // batch / slice-unit for staging & pointwise

    // xW gates for t=0; h@Wh accumulator for t=0 is 0 (h(-1)=0)
    float xg0, xg1, xg2, xg3;
    {
        const size_t xb = (size_t)pb * 1024 + wg * 8 + pu;
        xg0 = xWF[xb]; xg1 = xWF[xb + 256]; xg2 = xWF[xb + 512]; xg3 = xWF[xb + 768];
    }
    f32x4 hWacc = {0.f, 0.f, 0.f, 0.f};

    for (int t = 0; t < T_STEPS; ++t) {
        // ================= phase A =================
        // poll r(t-1): buffer (t+1)&1, tag t. Long publish shadow -> first-try.
        {
            const u64* rch = rT + (size_t)((((t + 1) & 1) * 32 + pb) * 16 + 2 * pu) * 2;
            const u32 want = (u32)t;
            u64 v0, v1, v2, v3;
            long guard = 0;
            for (;;) {
                v0 = lda(rch); v1 = lda(rch + 1); v2 = lda(rch + 2); v3 = lda(rch + 3);
                bool ok = ((u32)v0 == want) && ((u32)(v1 >> 32) == want) &&
                          ((u32)v2 == want) && ((u32)(v3 >> 32) == want);
                if (ok) break;
                if (++guard > 2000000L) break;   // bail instead of hanging
                if (guard > 4) __builtin_amdgcn_s_sleep(1);
            }
            u32* dst = (u32*)hr_lds + pb * 164 + 4 * pu;
            dst[0] = (u32)(v0 >> 32); dst[1] = (u32)v1;
            dst[2] = (u32)(v2 >> 32); dst[3] = (u32)v3;
        }
        __syncthreads();

        // rW MFMA (kt=0,1) accumulating onto carried h@Wh
        f32x4 acc = hWacc;
#pragma unroll
        for (int kt = 0; kt < 2; ++kt) {
            short8 a = *(const short8*)(hr_lds + (bt * 16 + fm) * PADK + kt * 32 + fq * 8);
            short8 b = *(const short8*)(wfrag + ((kt * 4 + fq) * 32 + ct * 16 + fm) * 8);
            acc = __builtin_amdgcn_mfma_f32_16x16x32_bf16(a, b, acc, 0, 0, 0);
        }
#pragma unroll
        for (int r = 0; r < 4; ++r) {
            int bb = bt * 16 + fq * 4 + r;        // C/D: row = quad*4+reg
            int cc = ct * 16 + fm;                //       col = lane&15
            z_lds[bb * 36 + cc] = acc[r];
        }
        __syncthreads();

        // LSTM pointwise for hidden units [8*wg, 8*wg+8), all batches
        {
            float iv = z_lds[pb * 36 + pu]      + xg0;
            float fv = z_lds[pb * 36 + 8 + pu]  + xg1;
            float gv = z_lds[pb * 36 + 16 + pu] + xg2;
            float ov = z_lds[pb * 36 + 24 + pu] + xg3;
            float co = c_lds[pb * 8 + pu];
            float cn = sigm(fv) * co + sigm(iv) * tanh_(gv);
            float hn = sigm(ov) * tanh_(cn);
            c_lds[pb * 8 + pu] = cn;
            hstage[pb * 8 + pu] = f2b(hn);
            HsF[(size_t)(t * BATCH + pb) * 256 + wg * 8 + pu] = hn;   // epilogue-only
        }
        __syncthreads();
        if (tid < 32) {   // packed h store: 16B per batch row
            uint4 hv = *(const uint4*)(hstage + tid * 8);
            st16(hrg + tid * KHR + 64 + wg * 8, hv);
        }
        gridbar(flags, (unsigned)(t + 1), wg);

        // ================= phase B =================
        // issue h(t) prefetch (16 KB total), no waitcnt yet
        uint4 ha, hb4, hc, hd;
        {
            const u16* src = hrg + pb * KHR + 64 + pu * 32;
            ld16x4_issue(src, src + 8, src + 16, src + 24, ha, hb4, hc, hd);
        }
        // xW gates for t+1 (plain cached loads, drain at wait_vm0)
        {
            int tn = (t + 1 < T_STEPS) ? t + 1 : 127;
            const size_t xb = (size_t)(tn * BATCH + pb) * 1024 + wg * 8 + pu;
            xg0 = xWF[xb]; xg1 = xWF[xb + 256]; xg2 = xWF[xb + 512]; xg3 = xWF[xb + 768];
        }
        // h-independent work while loads fly: ||mem_n||^2 (mem_old)
        float nr2 = 0.f;
        {
            const float4* mrow = (const float4*)(memA + tid * MEMPAD);
#pragma unroll
            for (int i = 0; i < 16; ++i) {
                float4 m4 = mrow[i];
                nr2 += m4.x * m4.x + m4.y * m4.y + m4.z * m4.z + m4.w * m4.w;
            }
        }
        wait_vm0();
        {
            u16* dst = hr_lds + pb * PADK + 64 + pu * 32;
            *(uint4*)(dst)      = ha;
            *(uint4*)(dst + 8)  = hb4;
            *(uint4*)(dst + 16) = hc;
            *(uint4*)(dst + 24) = hd;
        }
        __syncthreads();

        // hW MFMA (kt=2..9) -> fresh accumulator carried to phase A of t+1
        {
            f32x4 hz = {0.f, 0.f, 0.f, 0.f};
#pragma unroll
            for (int kt = 2; kt < 10; ++kt) {
                short8 a = *(const short8*)(hr_lds + (bt * 16 + fm) * PADK + kt * 32 + fq * 8);
                short8 b = *(const short8*)(wfrag + ((kt * 4 + fq) * 32 + ct * 16 + fm) * 8);
                hz = __builtin_amdgcn_mfma_f32_16x16x32_bf16(a, b, hz, 0, 0, 0);
            }
            hWacc = hz;
        }

        // M phase: this wg owns batch b = wg; h_b in hr_lds[wg]
        const u16* hrow = hr_lds + wg * PADK + 64;
        {
            float a = 0.f;
#pragma unroll
            for (int i = 0; i < 8; ++i) {
                short8 w8 = *(const short8*)(wkeyT + lane * WKPAD + wid * 64 + i * 8);
                short8 h8 = *(const short8*)(hrow + wid * 64 + i * 8);
#pragma unroll
                for (int e = 0; e < 8; ++e)
                    a += b2f((u16)h8[e]) * b2f((u16)w8[e]);
            }
            kpart[wid * 64 + lane] = a;
        }
        {
            float bp = b2f(hrow[tid]) * wbF[tid];
#pragma unroll
            for (int off = 32; off > 0; off >>= 1) bp += __shfl_xor(bp, off, 64);
            if (lane == 0) bred[wid] = bp;
        }
        __syncthreads();
        if (tid < 64) {   // finalize k, ||k||
            float kk = kpart[tid] + kpart[64 + tid] + kpart[128 + tid] + kpart[192 + tid];
            kv[tid] = kk;
            float k2 = kk * kk;
#pragma unroll
            for (int off = 32; off > 0; off >>= 1) k2 += __shfl_xor(k2, off, 64);
            if (tid == 0) sc[1] = sqrtf(k2);
        } else if (tid == 64) {   // beta = softplus
            float zb = bred[0] + bred[1] + bred[2] + bred[3];
            sc[0] = logf(1.f + __expf(zb));
        }
        __syncthreads();
        const float beta = sc[0], knorm = sc[1];

        // num pass (nr2 precomputed): thread = mem row, on mem_old
        float num = 0.f;
        {
            const float4* mrow = (const float4*)(memA + tid * MEMPAD);
            const float4* k4p  = (const float4*)kv;
#pragma unroll
            for (int i = 0; i < 16; ++i) {
                float4 m4 = mrow[i], k4 = k4p[i];
                num += m4.x * k4.x + m4.y * k4.y + m4.z * k4.z + m4.w * k4.w;
            }
        }
        float den = fmaxf(sqrtf(nr2) * knorm, 1e-8f);
        float s   = beta * (num / den);
        // per-wave max + sumexp + sumexp^2 (fused ||w||^2), then combine
        float wm = s;
#pragma unroll
        for (int off = 32; off > 0; off >>= 1) wm = fmaxf(wm, __shfl_xor(wm, off, 64));
        float ev = __expf(s - wm);
        float wsum = ev, wsumsq = ev * ev;
#pragma unroll
        for (int off = 32; off > 0; off >>= 1) {
            wsum   += __shfl_xor(wsum, off, 64);
            wsumsq += __shfl_xor(wsumsq, off, 64);
        }
        if (lane == 0) { wred[wid] = wm; wred[4 + wid] = wsum; wred[8 + wid] = wsumsq; }
        __syncthreads();
        float gm = fmaxf(fmaxf(wred[0], wred[1]), fmaxf(wred[2], wred[3]));
        float e0 = __expf(wred[0] - gm), e1 = __expf(wred[1] - gm);
        float e2 = __expf(wred[2] - gm), e3 = __expf(wred[3] - gm);
        float gsum  = wred[4] * e0 + wred[5] * e1 + wred[6] * e2 + wred[7] * e3;
        float gsumq = wred[8] * e0 * e0 + wred[9] * e1 * e1
                    + wred[10] * e2 * e2 + wred[11] * e3 * e3;
        float w   = __expf(s - gm) / gsum;          // this thread's weight for row tid
        float wsq = gsumq / (gsum * gsum);          // ||w||^2

        // READ pass on mem_old: w for rows [64*wid,64*wid+64) lives in this wave -> shuffles
        {
            const int lm = lane & 15, q = lane >> 4;
            float r0 = 0.f, r1 = 0.f, r2 = 0.f, r3 = 0.f;
#pragma unroll
            for (int i = 0; i < 16; ++i) {
                float wn = __shfl(w, i * 4 + q, 64);
                float4 m4 = *(const float4*)(memA + (wid * 64 + i * 4 + q) * MEMPAD + 4 * lm);
                r0 += wn * m4.x; r1 += wn * m4.y; r2 += wn * m4.z; r3 += wn * m4.w;
            }
            r0 += __shfl_xor(r0, 16, 64); r0 += __shfl_xor(r0, 32, 64);
            r1 += __shfl_xor(r1, 16, 64); r1 += __shfl_xor(r1, 32, 64);
            r2 += __shfl_xor(r2, 16, 64); r2 += __shfl_xor(r2, 32, 64);
            r3 += __shfl_xor(r3, 16, 64); r3 += __shfl_xor(r3, 32, 64);
            if (q == 0) {
                rp[wid * 64 + 4 * lm + 0] = r0;
                rp[wid * 64 + 4 * lm + 1] = r1;
                rp[wid * 64 + 4 * lm + 2] = r2;
                rp[wid * 64 + 4 * lm + 3] = r3;
            }
        }
        __syncthreads();
        if (tid < 64) {
            float rd = rp[tid] + rp[64 + tid] + rp[128 + tid] + rp[192 + tid]
                     + wsq * kv[tid];
            rstage[tid] = f2b(rd);
            RsF[(size_t)(t * BATCH + wg) * 64 + tid] = rd;   // epilogue-only
        }
        __syncthreads();
        // publish r(t) EARLY (tagged, buffer t&1, tag t+1) — before mem update
        if (tid < 16) {
            const u32* rs32 = (const u32*)rstage;
            u32 w0 = rs32[2 * tid], w1 = rs32[2 * tid + 1];
            u64* dstc = rT + (size_t)(((t & 1) * 32 + wg) * 16 + tid) * 2;
            const u64 tag = (u64)(u32)(t + 1);
            sta(dstc,     ((u64)w0 << 32) | tag);
            sta(dstc + 1, (tag << 32) | w1);
        }
        // mem UPDATE pass — off the critical path (covers r's flight to the LLC)
        {
            const int lm = lane & 15, q = lane >> 4;
            float4 k4 = ((const float4*)kv)[lm];
#pragma unroll
            for (int i = 0; i < 16; ++i) {
                float wn = __shfl(w, i * 4 + q, 64);
                float4* mp = (float4*)(memA + (wid * 64 + i * 4 + q) * MEMPAD + 4 * lm);
                float4 m4 = *mp;
                m4.x += wn * k4.x; m4.y += wn * k4.y; m4.z += wn * k4.z; m4.w += wn * k4.w;
                *mp = m4;
            }
        }
        // no barrier2: next step's r-poll + barrier1 bound the skew
    }
}

// ---------------- epilogue: ys = Hs@Wpre + Rs@Wro_eff + b_pre ; loss partials ----------------
__global__ void dnc_epilogue(char* __restrict__ ws, void* __restrict__ outv) {
    __shared__ float hs8[8][256];
    __shared__ float rs8[8][64];
    __shared__ float lacc;
    const float* HsF   = (const float*)(ws + WS_HS);
    const float* RsF   = (const float*)(ws + WS_RS);
    const float* WktF  = (const float*)(ws + WS_WKT);
    const float* WreF  = (const float*)(ws + WS_WROEFF);
    const float* WpreF = (const float*)(ws + WS_WPREF);
    const float* bpreF = (const float*)(ws + WS_BPREF);
    float* lossacc = (float*)(ws + WS_LOSS);
    const int bf = *(const int*)(ws + WS_FLAG);
    const int tid = threadIdx.x;
    const size_t r0 = (size_t)blockIdx.x * 8;
    if (tid == 0) lacc = 0.f;
    for (int i = tid; i < 8 * 256; i += 256) hs8[i >> 8][i & 255] = HsF[r0 * 256 + i];
    for (int i = tid; i < 8 * 64; i += 256)  rs8[i >> 6][i & 63]  = RsF[r0 * 64 + i];
    __syncthreads();
    // ys
    {
        const int rl = tid >> 5, c0 = (tid & 31) * 4;
        float a0 = bpreF[c0], a1 = bpreF[c0 + 1], a2 = bpreF[c0 + 2], a3 = bpreF[c0 + 3];
        for (int k = 0; k < 256; ++k) {
            float hv = hs8[rl][k];
            float4 w4 = *(const float4*)(WpreF + k * 128 + c0);
            a0 += hv * w4.x; a1 += hv * w4.y; a2 += hv * w4.z; a3 += hv * w4.w;
        }
        for (int m = 0; m < 64; ++m) {
            float rv = rs8[rl][m];
            float4 w4 = *(const float4*)(WreF + m * 128 + c0);
            a0 += rv * w4.x; a1 += rv * w4.y; a2 += rv * w4.z; a3 += rv * w4.w;
        }
        size_t o = (r0 + rl) * 128 + c0;
        if (bf) {
            u16* out = (u16*)outv;
            out[o] = f2b(a0); out[o + 1] = f2b(a1); out[o + 2] = f2b(a2); out[o + 3] = f2b(a3);
        } else {
            float* out = (float*)outv;
            out[o] = a0; out[o + 1] = a1; out[o + 2] = a2; out[o + 3] = a3;
        }
    }
    // loss: sum (h @ (Wkey - Wteach))^2
    {
        const int rl = tid >> 5, m0 = (tid & 31) * 2;
        float d0 = 0.f, d1 = 0.f;
        for (int k = 0; k < 256; ++k) {
            float hv = hs8[rl][k];
            d0 += hv * WktF[k * 64 + m0];
            d1 += hv * WktF[k * 64 + m0 + 1];
        }
        float p = d0 * d0 + d1 * d1;
#pragma unroll
        for (int off = 32; off > 0; off >>= 1) p += __shfl_xor(p, off, 64);
        if ((tid & 63) == 0) atomicAdd(&lacc, p);
        __syncthreads();
        if (tid == 0) atomicAdd(lossacc, lacc);
    }
}

__global__ void dnc_loss_fin(const char* __restrict__ ws, void* __restrict__ outv) {
    if (threadIdx.x == 0 && blockIdx.x == 0) {
        float l = *(const float*)(ws + WS_LOSS) * (1.f / 2048.f);
        if (*(const int*)(ws + WS_FLAG)) ((u16*)outv)[524288] = f2b(l);
        else                             ((float*)outv)[524288] = l;
    }
}

// ---------------- launch ----------------
extern "C" void kernel_launch(void* const* d_in, const int* in_sizes, int n_in,
                              void* d_out, int out_size, void* d_ws, size_t ws_size,
                              hipStream_t stream) {
    char* ws = (char*)d_ws;
    hipMemsetAsync(d_ws, 0, WS_ZSET, stream);   // flags, rT tags, loss, dtype flag, hrg
    dnc_normalize<<<512, 256, 0, stream>>>(d_in[0], d_in[1], d_in[2], d_in[3], d_in[4],
                                           d_in[5], d_in[6], d_in[7], d_in[8], d_in[9], ws);
    (void)hipFuncSetAttribute((const void*)dnc_prologue,
                              hipFuncAttributeMaxDynamicSharedMemorySize, 128 * 129 * 4);
    dnc_prologue<<<600, 256, 128 * 129 * 4, stream>>>(ws);
    (void)hipFuncSetAttribute((const void*)dnc_main,
                              hipFuncAttributeMaxDynamicSharedMemorySize, LDS_TOTAL);
    dnc_main<<<32, 256, LDS_TOTAL, stream>>>(ws);
    dnc_epilogue<<<512, 256, 0, stream>>>(ws, d_out);
    dnc_loss_fin<<<1, 64, 0, stream>>>(ws, d_out);
}